// Round 4
// baseline (711.272 us; speedup 1.0000x reference)
//
#include <hip/hip_runtime.h>

// order-preserving float->int key for atomicMax-based float max
__device__ __forceinline__ int okey(float x) {
    int ix = __float_as_int(x);
    return ix >= 0 ? ix : (ix ^ 0x7fffffff);
}
__device__ __forceinline__ float okey_dec(int k) {
    return __int_as_float(k >= 0 ? k : (k ^ 0x7fffffff));
}

// ---------------- Kernel I: reset pooled-sum / pooled-max buffers (replay-safe) ----------------
__global__ __launch_bounds__(256) void k_init(float* __restrict__ gsum,
                                              int* __restrict__ gmax, int total) {
    int i = blockIdx.x * blockDim.x + threadIdx.x;
    if (i < total) { gsum[i] = 0.f; gmax[i] = (int)0x80000000; }
}

// ---------------- Kernel 0: segment offsets + fused mask bias ----------------
__global__ void k_offsets(const int* __restrict__ batch, const int* __restrict__ cdr,
                          const int* __restrict__ ifm, const float* __restrict__ cdr_bias,
                          const float* __restrict__ iface_bias,
                          int* __restrict__ start, float* __restrict__ mbias,
                          int N, int B) {
    int i = blockIdx.x * blockDim.x + threadIdx.x;
    if (i >= N) return;
    mbias[i] = cdr_bias[0] * (float)cdr[i] + iface_bias[0] * (float)ifm[i];
    int b = batch[i];
    if (i == 0) {
        for (int g = 0; g <= b; ++g) start[g] = 0;
    } else {
        int pb = batch[i - 1];
        for (int g = pb + 1; g <= b; ++g) start[g] = i;
    }
    if (i == N - 1) {
        for (int g = b + 1; g <= B; ++g) start[g] = N;
    }
}

// ---------------- Kernel P: segment mean/max pooling via run-accumulate + atomics ----------------
// 128-node chunks -> N/128 = 2048 blocks (8 blocks/CU, 100% occupancy target).
// Wave w owns rows c0+w, c0+w+4, ... (2-deep prefetch). Lane l holds dims 4l..4l+3.
// batch is sorted, so each wave sees contiguous runs; flush one atomic set per run.
__global__ __launch_bounds__(256) void k_pool(
    const float* __restrict__ h, const int* __restrict__ batch,
    float* __restrict__ gsum, int* __restrict__ gmax, int N)
{
    const int c0 = blockIdx.x * 128;
    const int tid = threadIdx.x;
    const int w = tid >> 6;
    const int l = tid & 63;
    const int lim = min(128, N - c0);

    __shared__ int bb[128];
    if (tid < 128 && c0 + tid < N) bb[tid] = batch[c0 + tid];
    __syncthreads();

    float4 sm = make_float4(0.f, 0.f, 0.f, 0.f);
    float4 mxv = make_float4(-INFINITY, -INFINITY, -INFINITY, -INFINITY);

    const bool any = (w < lim);
    int cur = any ? bb[w] : 0;

    auto flush = [&](int g2) {
        float* sp = gsum + ((size_t)g2 << 8) + (l << 2);
        atomicAdd(sp + 0, sm.x); atomicAdd(sp + 1, sm.y);
        atomicAdd(sp + 2, sm.z); atomicAdd(sp + 3, sm.w);
        int* mp = gmax + ((size_t)g2 << 8) + (l << 2);
        atomicMax(mp + 0, okey(mxv.x)); atomicMax(mp + 1, okey(mxv.y));
        atomicMax(mp + 2, okey(mxv.z)); atomicMax(mp + 3, okey(mxv.w));
    };

    float4 xa = make_float4(0.f, 0.f, 0.f, 0.f);
    float4 xb = make_float4(0.f, 0.f, 0.f, 0.f);
    if (w < lim)     xa = *(const float4*)(h + (size_t)(c0 + w) * 256 + l * 4);
    if (w + 4 < lim) xb = *(const float4*)(h + (size_t)(c0 + w + 4) * 256 + l * 4);

    for (int idx = w; idx < lim; idx += 4) {
        const float4 xc = xa;
        xa = xb;
        if (idx + 8 < lim)
            xb = *(const float4*)(h + (size_t)(c0 + idx + 8) * 256 + l * 4);
        const int bg = bb[idx];
        if (bg != cur) {                      // run boundary: flush previous graph
            flush(cur);
            sm = make_float4(0.f, 0.f, 0.f, 0.f);
            mxv = make_float4(-INFINITY, -INFINITY, -INFINITY, -INFINITY);
            cur = bg;
        }
        sm.x += xc.x; sm.y += xc.y; sm.z += xc.z; sm.w += xc.w;
        mxv.x = fmaxf(mxv.x, xc.x); mxv.y = fmaxf(mxv.y, xc.y);
        mxv.z = fmaxf(mxv.z, xc.z); mxv.w = fmaxf(mxv.w, xc.w);
    }
    if (any) flush(cur);
}

// ---------------- Kernel Q: pooled stats -> q -> LN -> folded w_eff ----------------
// one block per graph, 256 threads; thread d owns dim d.
// w_eff is stored FOLDED: w_eff[g,h,j] = (sum_r Wk[h*32+r,j]*QL[h*32+r]) * scale * ln_kv_w[j]
// so k_attn computes logits on RAW x (const(g,h)=sum we*lnb is softmax-invariant, dropped).
__global__ __launch_bounds__(256) void k_q(
    const float* __restrict__ gsum, const int* __restrict__ gmax,
    const int* __restrict__ start,
    const float* __restrict__ Wq, const float* __restrict__ Wk,
    const float* __restrict__ ln_q_w, const float* __restrict__ ln_q_b,
    const float* __restrict__ ln_kv_w, const float* __restrict__ logit_scale,
    float* __restrict__ mean_raw, float* __restrict__ w_eff)
{
    const int g = blockIdx.x;
    const int d = threadIdx.x;
    const int s = start[g], e = start[g + 1];

    const float mean = gsum[(size_t)g * 256 + d] / (float)(e - s);
    const float mxv = okey_dec(gmax[(size_t)g * 256 + d]);
    mean_raw[(size_t)g * 256 + d] = mean;

    __shared__ __align__(16) float X[512];   // [mean | max]
    __shared__ float QL[256];
    __shared__ float rs[4], rq[4];
    X[d] = mean;
    X[256 + d] = mxv;
    __syncthreads();

    // q[d] = sum_j X[j] * Wq[d,j]   (Wq is (256,512) row-major)
    float q = 0.f;
    const float* wqr = Wq + (size_t)d * 512;
    #pragma unroll 8
    for (int j = 0; j < 512; j += 4) {
        float4 w4 = *(const float4*)(wqr + j);
        q += w4.x * X[j] + w4.y * X[j + 1] + w4.z * X[j + 2] + w4.w * X[j + 3];
    }
    // block LayerNorm over the 256 q values
    float s1 = q, s2 = q * q;
    #pragma unroll
    for (int off = 1; off < 64; off <<= 1) {
        s1 += __shfl_xor(s1, off);
        s2 += __shfl_xor(s2, off);
    }
    if ((d & 63) == 0) { rs[d >> 6] = s1; rq[d >> 6] = s2; }
    __syncthreads();
    const float t1 = rs[0] + rs[1] + rs[2] + rs[3];
    const float t2 = rq[0] + rq[1] + rq[2] + rq[3];
    const float mu = t1 * (1.f / 256.f);
    const float var = t2 * (1.f / 256.f) - mu * mu;
    const float rstd = rsqrtf(var + 1e-5f);
    QL[d] = (q - mu) * rstd * ln_q_w[d] + ln_q_b[d];
    __syncthreads();

    const float scale = logit_scale[0] * 0.17677669529663687f; // 1/sqrt(32)
    const float fold = scale * ln_kv_w[d];
    #pragma unroll
    for (int hh = 0; hh < 8; ++hh) {
        float a = 0.f;
        #pragma unroll 8
        for (int r = 0; r < 32; ++r) {
            a += Wk[(size_t)(hh * 32 + r) * 256 + d] * QL[hh * 32 + r];
        }
        w_eff[((size_t)g * 8 + hh) * 256 + d] = a * fold;
    }
}

// ---------------- Kernel B: logits on raw x + online segment softmax + u ----------------
// one block per graph, 4 waves; wave w handles nodes s+w, s+w+4, ... with a
// DEPTH-3 named-register pipeline (x0/x1/x2) to cover ~900cy HBM latency.
// lane layout: hh = l>>3 (head), p = l&7 (32-wide j-chunk)
// NOTE: plain __launch_bounds__(256) — a (256,4) min-waves hint capped VGPR at 64 and
// spilled u[32]/hv[32] to scratch (418 MB WRITE_SIZE, 2.3x slower). Do not re-add.
__global__ __launch_bounds__(256) void k_attn(
    const float* __restrict__ h, const int* __restrict__ start,
    const float* __restrict__ mbias,
    const float* __restrict__ ln_w, const float* __restrict__ ln_b,
    const float* __restrict__ w_eff,
    float* __restrict__ u_norm)
{
    const int g = blockIdx.x;
    const int tid = threadIdx.x;
    const int w = tid >> 6;
    const int l = tid & 63;
    const int hh = l >> 3;
    const int p = l & 7;
    const int s = start[g], e = start[g + 1];

    // folded key weights A for (head hh, chunk p)
    float we[32];
    {
        const float* wp = w_eff + ((size_t)g * 8 + hh) * 256 + p * 32;
        #pragma unroll
        for (int r = 0; r < 8; ++r) {
            float4 t = *(const float4*)(wp + r * 4);
            we[4 * r + 0] = t.x; we[4 * r + 1] = t.y; we[4 * r + 2] = t.z; we[4 * r + 3] = t.w;
        }
    }
    // s1h = sum_j A[hh][j]  (uniform across the 8 lanes of a head after reduce)
    float s1h = 0.f;
    #pragma unroll
    for (int r = 0; r < 32; ++r) s1h += we[r];
    s1h += __shfl_xor(s1h, 1);
    s1h += __shfl_xor(s1h, 2);
    s1h += __shfl_xor(s1h, 4);

    float m = -INFINITY, z = 0.f, sw = 0.f;
    float u[32];
    #pragma unroll
    for (int r = 0; r < 32; ++r) u[r] = 0.f;

    // padded row buffer: 32-float chunk c lives at float offset c*36
    __shared__ __align__(16) float hbuf[4][288];
    __shared__ __align__(16) float UF[4][8][264];   // padded: kills conflicts on p*32 writes
    __shared__ float MW[4][8], ZW[4][8], SW[4][8], FG[4][8], IZ[8], SG[8];

    const int wofs = l * 4 + ((l >> 3) << 2); // padded offset of j = l*4
    const int rofs = p * 36;                  // padded base of chunk p

    auto process = [&](const float4& xc, float mbv) {
        *(float4*)(&hbuf[w][wofs]) = xc;       // RAW x (no LN yet)
        asm volatile("s_waitcnt lgkmcnt(0)" ::: "memory");
        float hv[32];
        #pragma unroll
        for (int r = 0; r < 8; ++r) {
            float4 t = *(const float4*)(&hbuf[w][rofs + r * 4]);
            hv[4 * r + 0] = t.x; hv[4 * r + 1] = t.y; hv[4 * r + 2] = t.z; hv[4 * r + 3] = t.w;
        }
        // local stats + dot over the chunk, then ONE shared 3-level reduce
        float s1 = 0.f, s2 = 0.f, dt = 0.f;
        #pragma unroll
        for (int r = 0; r < 32; ++r) {
            const float v = hv[r];
            s1 += v;
            s2 = fmaf(v, v, s2);
            dt = fmaf(v, we[r], dt);
        }
        #pragma unroll
        for (int off = 1; off < 8; off <<= 1) {
            s1 += __shfl_xor(s1, off);
            s2 += __shfl_xor(s2, off);
            dt += __shfl_xor(dt, off);
        }
        const float mu = s1 * (1.f / 256.f);
        const float var = s2 * (1.f / 256.f) - mu * mu;
        const float rstd = rsqrtf(var + 1e-5f);
        const float lv = rstd * (dt - mu * s1h) + mbv;

        const float nm = fmaxf(m, lv);
        const float ee = __expf(lv - nm);
        const float c = ee * rstd;
        if (__any(lv > m)) {                   // max moved: rescale path
            const float a = __expf(m - nm);    // exp(-inf)=0 on first node
            z = z * a + ee;
            sw = sw * a + c * mu;
            #pragma unroll
            for (int r = 0; r < 32; ++r) u[r] = u[r] * a + c * hv[r];
            m = nm;
        } else {                               // common path: no rescale, 1 FMA per elem
            z += ee;
            sw += c * mu;
            #pragma unroll
            for (int r = 0; r < 32; ++r) u[r] = fmaf(c, hv[r], u[r]);
        }
    };

    int n = s + w;
    float4 x0 = make_float4(0.f, 0.f, 0.f, 0.f);
    float4 x1 = x0, x2 = x0;
    float b0 = 0.f, b1 = 0.f, b2 = 0.f;
    if (n < e)     { x0 = *(const float4*)(h + (size_t)n * 256 + l * 4);        b0 = mbias[n]; }
    if (n + 4 < e) { x1 = *(const float4*)(h + (size_t)(n + 4) * 256 + l * 4);  b1 = mbias[n + 4]; }
    if (n + 8 < e) { x2 = *(const float4*)(h + (size_t)(n + 8) * 256 + l * 4);  b2 = mbias[n + 8]; }

    for (; n < e; n += 12) {
        process(x0, b0);
        if (n + 12 < e) { x0 = *(const float4*)(h + (size_t)(n + 12) * 256 + l * 4); b0 = mbias[n + 12]; }
        if (n + 4 < e) {
            process(x1, b1);
            if (n + 16 < e) { x1 = *(const float4*)(h + (size_t)(n + 16) * 256 + l * 4); b1 = mbias[n + 16]; }
            if (n + 8 < e) {
                process(x2, b2);
                if (n + 20 < e) { x2 = *(const float4*)(h + (size_t)(n + 20) * 256 + l * 4); b2 = mbias[n + 20]; }
            }
        }
    }

    if (p == 0) { MW[w][hh] = m; ZW[w][hh] = z; SW[w][hh] = sw; }
    #pragma unroll
    for (int r = 0; r < 8; ++r) {
        float4 t = make_float4(u[4 * r], u[4 * r + 1], u[4 * r + 2], u[4 * r + 3]);
        *(float4*)(&UF[w][hh][p * 32 + r * 4]) = t;
    }
    __syncthreads();

    if (tid < 8) {
        const float mg = fmaxf(fmaxf(MW[0][tid], MW[1][tid]),
                               fmaxf(MW[2][tid], MW[3][tid]));
        float zg = 0.f, sg = 0.f;
        #pragma unroll
        for (int ww = 0; ww < 4; ++ww) {
            const float f = __expf(MW[ww][tid] - mg);  // empty wave: exp(-inf)=0
            FG[ww][tid] = f;
            zg += ZW[ww][tid] * f;
            sg += SW[ww][tid] * f;
        }
        IZ[tid] = 1.f / zg;
        SG[tid] = sg;
    }
    __syncthreads();

    const float lwj = ln_w[tid], lbj = ln_b[tid];
    #pragma unroll
    for (int h2 = 0; h2 < 8; ++h2) {
        const float Uv = UF[0][h2][tid] * FG[0][h2] + UF[1][h2][tid] * FG[1][h2]
                       + UF[2][h2][tid] * FG[2][h2] + UF[3][h2][tid] * FG[3][h2];
        u_norm[(size_t)g * 2048 + h2 * 256 + tid] = (Uv - SG[h2]) * IZ[h2] * lwj + lbj;
    }
}

// ---------------- Kernel C: g = Wv . u_norm (head-selected), out = Wout.g + 0.2*Wres.mean ----------------
// one graph per block (1024 blocks -> 4 blocks/CU; weights are L2-resident)
__global__ __launch_bounds__(256) void k_out(
    const float* __restrict__ u_norm, const float* __restrict__ mean_raw,
    const float* __restrict__ Wv, const float* __restrict__ Wout,
    const float* __restrict__ Wres, float* __restrict__ out)
{
    const int d = threadIdx.x;
    const int g = blockIdx.x;
    __shared__ __align__(16) float UN[8][256];  // 8 KB
    __shared__ __align__(16) float MR[256];
    __shared__ __align__(16) float GF[256];

    const float4* up = (const float4*)(u_norm + (size_t)g * 2048);
    ((float4*)UN)[d] = up[d];
    ((float4*)UN)[256 + d] = up[256 + d];
    if (d < 64) ((float4*)MR)[d] = ((const float4*)(mean_raw + (size_t)g * 256))[d];
    __syncthreads();

    const int hh = d >> 5;
    float acc = 0.f;
    const float* wvr = Wv + (size_t)d * 256;
    #pragma unroll 8
    for (int j = 0; j < 256; j += 4) {
        const float4 wv = *(const float4*)(wvr + j);
        const float4 uv = *(const float4*)(&UN[hh][j]);
        acc += wv.x * uv.x + wv.y * uv.y + wv.z * uv.z + wv.w * uv.w;
    }
    GF[d] = acc;
    __syncthreads();

    float oo = 0.f, rr = 0.f;
    const float* wor = Wout + (size_t)d * 256;
    const float* wrr = Wres + (size_t)d * 256;
    #pragma unroll 8
    for (int j = 0; j < 256; j += 4) {
        const float4 wo = *(const float4*)(wor + j);
        const float4 wq = *(const float4*)(wrr + j);
        const float4 gf = *(const float4*)(&GF[j]);
        const float4 mr = *(const float4*)(&MR[j]);
        oo += wo.x * gf.x + wo.y * gf.y + wo.z * gf.z + wo.w * gf.w;
        rr += wq.x * mr.x + wq.y * mr.y + wq.z * mr.z + wq.w * mr.w;
    }
    out[(size_t)g * 256 + d] = oo + 0.2f * rr;
}

// ---------------- launch ----------------
extern "C" void kernel_launch(void* const* d_in, const int* in_sizes, int n_in,
                              void* d_out, int out_size, void* d_ws, size_t ws_size,
                              hipStream_t stream)
{
    const float* h        = (const float*)d_in[0];
    const int*   batch    = (const int*)d_in[1];
    const int*   cdr      = (const int*)d_in[2];   // bool mask arrives as int32
    const int*   ifm      = (const int*)d_in[3];   // bool mask arrives as int32
    const float* ln_kv_w  = (const float*)d_in[4];
    const float* ln_kv_b  = (const float*)d_in[5];
    const float* ln_q_w   = (const float*)d_in[6];
    const float* ln_q_b   = (const float*)d_in[7];
    const float* Wk       = (const float*)d_in[8];
    const float* Wv       = (const float*)d_in[9];
    const float* Wq       = (const float*)d_in[10];
    const float* Wres     = (const float*)d_in[11];
    const float* Wout     = (const float*)d_in[12];
    const float* cdr_b    = (const float*)d_in[13];
    const float* if_b     = (const float*)d_in[14];
    const float* lsc      = (const float*)d_in[15];

    const int N = in_sizes[0] / 256;   // 262144
    const int B = out_size / 256;      // 1024

    int*   start    = (int*)d_ws;                         // (B+1) ints (8 KB reserved)
    float* mean_raw = (float*)((char*)d_ws + 8192);       // B*256 floats (1 MB)
    float* w_eff    = mean_raw + (size_t)B * 256;         // B*8*256 floats (8 MB)
    float* u_norm   = w_eff + (size_t)B * 2048;           // B*8*256 floats (8 MB)
    float* gsum     = u_norm + (size_t)B * 2048;          // B*256 floats (1 MB)
    int*   gmax     = (int*)(gsum + (size_t)B * 256);     // B*256 ints (1 MB)
    float* mbias    = (float*)(gmax + (size_t)B * 256);   // N floats (1 MB)

    k_init<<<(B * 256 + 255) / 256, 256, 0, stream>>>(gsum, gmax, B * 256);
    k_offsets<<<(N + 255) / 256, 256, 0, stream>>>(batch, cdr, ifm, cdr_b, if_b,
                                                   start, mbias, N, B);
    k_pool<<<(N + 127) / 128, 256, 0, stream>>>(h, batch, gsum, gmax, N);
    k_q<<<B, 256, 0, stream>>>(gsum, gmax, start, Wq, Wk, ln_q_w, ln_q_b, ln_kv_w,
                               lsc, mean_raw, w_eff);
    k_attn<<<B, 256, 0, stream>>>(h, start, mbias, ln_kv_w, ln_kv_b, w_eff, u_norm);
    k_out<<<B, 256, 0, stream>>>(u_norm, mean_raw, Wv, Wout, Wres, (float*)d_out);
}

// Round 5
// 663.748 us; speedup vs baseline: 1.0716x; 1.0716x over previous
//
#include <hip/hip_runtime.h>

// ---------------- Kernel 0: segment offsets + fused mask bias ----------------
__global__ void k_offsets(const int* __restrict__ batch, const int* __restrict__ cdr,
                          const int* __restrict__ ifm, const float* __restrict__ cdr_bias,
                          const float* __restrict__ iface_bias,
                          int* __restrict__ start, float* __restrict__ mbias,
                          int N, int B) {
    int i = blockIdx.x * blockDim.x + threadIdx.x;
    if (i >= N) return;
    mbias[i] = cdr_bias[0] * (float)cdr[i] + iface_bias[0] * (float)ifm[i];
    int b = batch[i];
    if (i == 0) {
        for (int g = 0; g <= b; ++g) start[g] = 0;
    } else {
        int pb = batch[i - 1];
        for (int g = pb + 1; g <= b; ++g) start[g] = i;
    }
    if (i == N - 1) {
        for (int g = b + 1; g <= B; ++g) start[g] = N;
    }
}

// ---------------- Kernel P: slice-partial mean/max pooling (deterministic) ----------------
// 4 slices per graph -> 4096 blocks (vs 1024: fixes the 41%-occupancy latency bind seen
// in round 3's pooling). Wave w owns rows qs+w, qs+w+4, ...; flat 4-row unroll keeps
// ~4 KB/wave of loads in flight. Partials written coalesced; NO atomics (rocprof-replay
// deterministic; round 4's atomic version was slower and broke profiling).
__global__ __launch_bounds__(256) void k_pool(
    const float* __restrict__ h, const int* __restrict__ start,
    float* __restrict__ psum, float* __restrict__ pmax)
{
    const int g = blockIdx.x >> 2;
    const int sl = blockIdx.x & 3;
    const int tid = threadIdx.x;
    const int w = tid >> 6;
    const int l = tid & 63;
    const int s = start[g], e = start[g + 1];
    const int len = e - s;
    const int qs = s + (len * sl) / 4;
    const int qe = s + (len * (sl + 1)) / 4;

    float4 sm = make_float4(0.f, 0.f, 0.f, 0.f);
    float4 mx = make_float4(-INFINITY, -INFINITY, -INFINITY, -INFINITY);

    int n = qs + w;
    // main loop: 4 independent row loads issued back-to-back per iteration
    for (; n + 12 < qe; n += 16) {
        const float4 a = *(const float4*)(h + (size_t)n * 256 + l * 4);
        const float4 b = *(const float4*)(h + (size_t)(n + 4) * 256 + l * 4);
        const float4 c = *(const float4*)(h + (size_t)(n + 8) * 256 + l * 4);
        const float4 d4 = *(const float4*)(h + (size_t)(n + 12) * 256 + l * 4);
        sm.x += (a.x + b.x) + (c.x + d4.x); sm.y += (a.y + b.y) + (c.y + d4.y);
        sm.z += (a.z + b.z) + (c.z + d4.z); sm.w += (a.w + b.w) + (c.w + d4.w);
        mx.x = fmaxf(mx.x, fmaxf(fmaxf(a.x, b.x), fmaxf(c.x, d4.x)));
        mx.y = fmaxf(mx.y, fmaxf(fmaxf(a.y, b.y), fmaxf(c.y, d4.y)));
        mx.z = fmaxf(mx.z, fmaxf(fmaxf(a.z, b.z), fmaxf(c.z, d4.z)));
        mx.w = fmaxf(mx.w, fmaxf(fmaxf(a.w, b.w), fmaxf(c.w, d4.w)));
    }
    for (; n < qe; n += 4) {
        const float4 a = *(const float4*)(h + (size_t)n * 256 + l * 4);
        sm.x += a.x; sm.y += a.y; sm.z += a.z; sm.w += a.w;
        mx.x = fmaxf(mx.x, a.x); mx.y = fmaxf(mx.y, a.y);
        mx.z = fmaxf(mx.z, a.z); mx.w = fmaxf(mx.w, a.w);
    }

    __shared__ __align__(16) float PS[4][256];
    __shared__ __align__(16) float PM[4][256];
    *(float4*)(&PS[w][l * 4]) = sm;
    *(float4*)(&PM[w][l * 4]) = mx;
    __syncthreads();
    const int d = tid;
    const float sum = (PS[0][d] + PS[1][d]) + (PS[2][d] + PS[3][d]);
    const float mxv = fmaxf(fmaxf(PM[0][d], PM[1][d]), fmaxf(PM[2][d], PM[3][d]));
    psum[(size_t)blockIdx.x * 256 + d] = sum;
    pmax[(size_t)blockIdx.x * 256 + d] = mxv;
}

// ---------------- Kernel Q: partials -> mean/max -> q -> LN -> folded w_eff ----------------
// one block per graph, 256 threads; thread d owns dim d.
// w_eff is stored FOLDED: w_eff[g,h,j] = (sum_r Wk[h*32+r,j]*QL[h*32+r]) * scale * ln_kv_w[j]
// so k_attn computes logits on RAW x (const(g,h)=sum we*lnb is softmax-invariant, dropped).
__global__ __launch_bounds__(256) void k_q(
    const float* __restrict__ psum, const float* __restrict__ pmax,
    const int* __restrict__ start,
    const float* __restrict__ Wq, const float* __restrict__ Wk,
    const float* __restrict__ ln_q_w, const float* __restrict__ ln_q_b,
    const float* __restrict__ ln_kv_w, const float* __restrict__ logit_scale,
    float* __restrict__ mean_raw, float* __restrict__ w_eff)
{
    const int g = blockIdx.x;
    const int d = threadIdx.x;
    const int s = start[g], e = start[g + 1];

    float sum = 0.f, mxv = -INFINITY;
    #pragma unroll
    for (int sl = 0; sl < 4; ++sl) {
        sum += psum[((size_t)g * 4 + sl) * 256 + d];
        mxv = fmaxf(mxv, pmax[((size_t)g * 4 + sl) * 256 + d]);
    }
    const float mean = sum / (float)(e - s);
    mean_raw[(size_t)g * 256 + d] = mean;

    __shared__ __align__(16) float X[512];   // [mean | max]
    __shared__ float QL[256];
    __shared__ float rs[4], rq[4];
    X[d] = mean;
    X[256 + d] = mxv;
    __syncthreads();

    // q[d] = sum_j X[j] * Wq[d,j]   (Wq is (256,512) row-major)
    float q = 0.f;
    const float* wqr = Wq + (size_t)d * 512;
    #pragma unroll 8
    for (int j = 0; j < 512; j += 4) {
        float4 w4 = *(const float4*)(wqr + j);
        q += w4.x * X[j] + w4.y * X[j + 1] + w4.z * X[j + 2] + w4.w * X[j + 3];
    }
    // block LayerNorm over the 256 q values
    float s1 = q, s2 = q * q;
    #pragma unroll
    for (int off = 1; off < 64; off <<= 1) {
        s1 += __shfl_xor(s1, off);
        s2 += __shfl_xor(s2, off);
    }
    if ((d & 63) == 0) { rs[d >> 6] = s1; rq[d >> 6] = s2; }
    __syncthreads();
    const float t1 = rs[0] + rs[1] + rs[2] + rs[3];
    const float t2 = rq[0] + rq[1] + rq[2] + rq[3];
    const float mu = t1 * (1.f / 256.f);
    const float var = t2 * (1.f / 256.f) - mu * mu;
    const float rstd = rsqrtf(var + 1e-5f);
    QL[d] = (q - mu) * rstd * ln_q_w[d] + ln_q_b[d];
    __syncthreads();

    const float scale = logit_scale[0] * 0.17677669529663687f; // 1/sqrt(32)
    const float fold = scale * ln_kv_w[d];
    #pragma unroll
    for (int hh = 0; hh < 8; ++hh) {
        float a = 0.f;
        #pragma unroll 8
        for (int r = 0; r < 32; ++r) {
            a += Wk[(size_t)(hh * 32 + r) * 256 + d] * QL[hh * 32 + r];
        }
        w_eff[((size_t)g * 8 + hh) * 256 + d] = a * fold;
    }
}

// ---------------- Kernel B: logits on raw x + online segment softmax + u ----------------
// one block per graph, 4 waves; wave w handles nodes s+w, s+w+4, ... (depth-2 prefetch,
// the measured round-3 structure; only diff: one mbias float load replaces two int loads).
// lane layout: hh = l>>3 (head), p = l&7 (32-wide j-chunk)
// Per node: write RAW x to LDS, read chunk, compute {s1,s2,dotA} locally, ONE 3-level
// xor(1,2,4) reduce gives full LN stats AND the per-head dot. u accumulates raw x with
// weight e*rstd; the lnw/lnb correction is applied once in the epilogue:
//   sum_n e_n * h_ln[n,j] = lnw_j*(U[j] - Sw) + lnb_j*Z,  Sw = sum e*rstd*mu, Z = sum e
// NOTE: plain __launch_bounds__(256) — a (256,4) min-waves hint capped VGPR at 64 and
// spilled u[32]/hv[32] to scratch (418 MB WRITE_SIZE, 2.3x slower). Do not re-add.
__global__ __launch_bounds__(256) void k_attn(
    const float* __restrict__ h, const int* __restrict__ start,
    const float* __restrict__ mbias,
    const float* __restrict__ ln_w, const float* __restrict__ ln_b,
    const float* __restrict__ w_eff,
    float* __restrict__ u_norm)
{
    const int g = blockIdx.x;
    const int tid = threadIdx.x;
    const int w = tid >> 6;
    const int l = tid & 63;
    const int hh = l >> 3;
    const int p = l & 7;
    const int s = start[g], e = start[g + 1];

    // folded key weights A for (head hh, chunk p)
    float we[32];
    {
        const float* wp = w_eff + ((size_t)g * 8 + hh) * 256 + p * 32;
        #pragma unroll
        for (int r = 0; r < 8; ++r) {
            float4 t = *(const float4*)(wp + r * 4);
            we[4 * r + 0] = t.x; we[4 * r + 1] = t.y; we[4 * r + 2] = t.z; we[4 * r + 3] = t.w;
        }
    }
    // s1h = sum_j A[hh][j]  (uniform across the 8 lanes of a head after reduce)
    float s1h = 0.f;
    #pragma unroll
    for (int r = 0; r < 32; ++r) s1h += we[r];
    s1h += __shfl_xor(s1h, 1);
    s1h += __shfl_xor(s1h, 2);
    s1h += __shfl_xor(s1h, 4);

    float m = -INFINITY, z = 0.f, sw = 0.f;
    float u[32];
    #pragma unroll
    for (int r = 0; r < 32; ++r) u[r] = 0.f;

    // padded row buffer: 32-float chunk c lives at float offset c*36
    __shared__ __align__(16) float hbuf[4][288];
    __shared__ __align__(16) float UF[4][8][264];   // padded: kills conflicts on p*32 writes
    __shared__ float MW[4][8], ZW[4][8], SW[4][8], FG[4][8], IZ[8], SG[8];

    const int wofs = l * 4 + ((l >> 3) << 2); // padded offset of j = l*4
    const int rofs = p * 36;                  // padded base of chunk p

    int n = s + w;
    float4 xn = make_float4(0.f, 0.f, 0.f, 0.f);
    float bn = 0.f;
    if (n < e) {                               // prefetch node 0
        xn = *(const float4*)(h + (size_t)n * 256 + l * 4);
        bn = mbias[n];
    }
    while (n < e) {
        const float4 xc = xn;
        const float bc = bn;
        const int n2 = n + 4;
        if (n2 < e) {                          // software-pipeline next node's x + bias
            xn = *(const float4*)(h + (size_t)n2 * 256 + l * 4);
            bn = mbias[n2];
        }

        *(float4*)(&hbuf[w][wofs]) = xc;       // RAW x (no LN yet)
        asm volatile("s_waitcnt lgkmcnt(0)" ::: "memory");

        float hv[32];
        #pragma unroll
        for (int r = 0; r < 8; ++r) {
            float4 t = *(const float4*)(&hbuf[w][rofs + r * 4]);
            hv[4 * r + 0] = t.x; hv[4 * r + 1] = t.y; hv[4 * r + 2] = t.z; hv[4 * r + 3] = t.w;
        }
        // local stats + dot over the chunk, then ONE shared 3-level reduce
        float s1 = 0.f, s2 = 0.f, dt = 0.f;
        #pragma unroll
        for (int r = 0; r < 32; ++r) {
            const float v = hv[r];
            s1 += v;
            s2 = fmaf(v, v, s2);
            dt = fmaf(v, we[r], dt);
        }
        #pragma unroll
        for (int off = 1; off < 8; off <<= 1) {
            s1 += __shfl_xor(s1, off);
            s2 += __shfl_xor(s2, off);
            dt += __shfl_xor(dt, off);
        }
        const float mu = s1 * (1.f / 256.f);
        const float var = s2 * (1.f / 256.f) - mu * mu;
        const float rstd = rsqrtf(var + 1e-5f);
        const float lv = rstd * (dt - mu * s1h) + bc;

        const float nm = fmaxf(m, lv);
        const float ee = __expf(lv - nm);
        const float c = ee * rstd;
        if (__any(lv > m)) {                   // max moved: rescale path
            const float a = __expf(m - nm);    // exp(-inf)=0 on first node
            z = z * a + ee;
            sw = sw * a + c * mu;
            #pragma unroll
            for (int r = 0; r < 32; ++r) u[r] = u[r] * a + c * hv[r];
            m = nm;
        } else {                               // common path: no rescale, 1 FMA per elem
            z += ee;
            sw += c * mu;
            #pragma unroll
            for (int r = 0; r < 32; ++r) u[r] = fmaf(c, hv[r], u[r]);
        }
        n = n2;
    }

    if (p == 0) { MW[w][hh] = m; ZW[w][hh] = z; SW[w][hh] = sw; }
    #pragma unroll
    for (int r = 0; r < 8; ++r) {
        float4 t = make_float4(u[4 * r], u[4 * r + 1], u[4 * r + 2], u[4 * r + 3]);
        *(float4*)(&UF[w][hh][p * 32 + r * 4]) = t;
    }
    __syncthreads();

    if (tid < 8) {
        const float mg = fmaxf(fmaxf(MW[0][tid], MW[1][tid]),
                               fmaxf(MW[2][tid], MW[3][tid]));
        float zg = 0.f, sg = 0.f;
        #pragma unroll
        for (int ww = 0; ww < 4; ++ww) {
            const float f = __expf(MW[ww][tid] - mg);  // empty wave: exp(-inf)=0
            FG[ww][tid] = f;
            zg += ZW[ww][tid] * f;
            sg += SW[ww][tid] * f;
        }
        IZ[tid] = 1.f / zg;
        SG[tid] = sg;
    }
    __syncthreads();

    const float lwj = ln_w[tid], lbj = ln_b[tid];
    #pragma unroll
    for (int h2 = 0; h2 < 8; ++h2) {
        const float Uv = UF[0][h2][tid] * FG[0][h2] + UF[1][h2][tid] * FG[1][h2]
                       + UF[2][h2][tid] * FG[2][h2] + UF[3][h2][tid] * FG[3][h2];
        u_norm[(size_t)g * 2048 + h2 * 256 + tid] = (Uv - SG[h2]) * IZ[h2] * lwj + lbj;
    }
}

// ---------------- Kernel C: g = Wv . u_norm (head-selected), out = Wout.g + 0.2*Wres.mean ----------------
// one graph per block (1024 blocks -> 4 blocks/CU; weights are L2-resident)
__global__ __launch_bounds__(256) void k_out(
    const float* __restrict__ u_norm, const float* __restrict__ mean_raw,
    const float* __restrict__ Wv, const float* __restrict__ Wout,
    const float* __restrict__ Wres, float* __restrict__ out)
{
    const int d = threadIdx.x;
    const int g = blockIdx.x;
    __shared__ __align__(16) float UN[8][256];  // 8 KB
    __shared__ __align__(16) float MR[256];
    __shared__ __align__(16) float GF[256];

    const float4* up = (const float4*)(u_norm + (size_t)g * 2048);
    ((float4*)UN)[d] = up[d];
    ((float4*)UN)[256 + d] = up[256 + d];
    if (d < 64) ((float4*)MR)[d] = ((const float4*)(mean_raw + (size_t)g * 256))[d];
    __syncthreads();

    const int hh = d >> 5;
    float acc = 0.f;
    const float* wvr = Wv + (size_t)d * 256;
    #pragma unroll 8
    for (int j = 0; j < 256; j += 4) {
        const float4 wv = *(const float4*)(wvr + j);
        const float4 uv = *(const float4*)(&UN[hh][j]);
        acc += wv.x * uv.x + wv.y * uv.y + wv.z * uv.z + wv.w * uv.w;
    }
    GF[d] = acc;
    __syncthreads();

    float oo = 0.f, rr = 0.f;
    const float* wor = Wout + (size_t)d * 256;
    const float* wrr = Wres + (size_t)d * 256;
    #pragma unroll 8
    for (int j = 0; j < 256; j += 4) {
        const float4 wo = *(const float4*)(wor + j);
        const float4 wq = *(const float4*)(wrr + j);
        const float4 gf = *(const float4*)(&GF[j]);
        const float4 mr = *(const float4*)(&MR[j]);
        oo += wo.x * gf.x + wo.y * gf.y + wo.z * gf.z + wo.w * gf.w;
        rr += wq.x * mr.x + wq.y * mr.y + wq.z * mr.z + wq.w * mr.w;
    }
    out[(size_t)g * 256 + d] = oo + 0.2f * rr;
}

// ---------------- launch ----------------
extern "C" void kernel_launch(void* const* d_in, const int* in_sizes, int n_in,
                              void* d_out, int out_size, void* d_ws, size_t ws_size,
                              hipStream_t stream)
{
    const float* h        = (const float*)d_in[0];
    const int*   batch    = (const int*)d_in[1];
    const int*   cdr      = (const int*)d_in[2];   // bool mask arrives as int32
    const int*   ifm      = (const int*)d_in[3];   // bool mask arrives as int32
    const float* ln_kv_w  = (const float*)d_in[4];
    const float* ln_kv_b  = (const float*)d_in[5];
    const float* ln_q_w   = (const float*)d_in[6];
    const float* ln_q_b   = (const float*)d_in[7];
    const float* Wk       = (const float*)d_in[8];
    const float* Wv       = (const float*)d_in[9];
    const float* Wq       = (const float*)d_in[10];
    const float* Wres     = (const float*)d_in[11];
    const float* Wout     = (const float*)d_in[12];
    const float* cdr_b    = (const float*)d_in[13];
    const float* if_b     = (const float*)d_in[14];
    const float* lsc      = (const float*)d_in[15];

    const int N = in_sizes[0] / 256;   // 262144
    const int B = out_size / 256;      // 1024

    int*   start    = (int*)d_ws;                         // (B+1) ints (8 KB reserved)
    float* mean_raw = (float*)((char*)d_ws + 8192);       // B*256 floats (1 MB)
    float* w_eff    = mean_raw + (size_t)B * 256;         // B*8*256 floats (8 MB)
    float* u_norm   = w_eff + (size_t)B * 2048;           // B*8*256 floats (8 MB)
    float* psum     = u_norm + (size_t)B * 2048;          // 4B*256 floats (4 MB)
    float* pmax     = psum + (size_t)B * 1024;            // 4B*256 floats (4 MB)
    float* mbias    = pmax + (size_t)B * 1024;            // N floats (1 MB)

    k_offsets<<<(N + 255) / 256, 256, 0, stream>>>(batch, cdr, ifm, cdr_b, if_b,
                                                   start, mbias, N, B);
    k_pool<<<B * 4, 256, 0, stream>>>(h, start, psum, pmax);
    k_q<<<B, 256, 0, stream>>>(psum, pmax, start, Wq, Wk, ln_q_w, ln_q_b, ln_kv_w,
                               lsc, mean_raw, w_eff);
    k_attn<<<B, 256, 0, stream>>>(h, start, mbias, ln_kv_w, ln_kv_b, w_eff, u_norm);
    k_out<<<B, 256, 0, stream>>>(u_norm, mean_raw, Wv, Wout, Wres, (float*)d_out);
}

// Round 6
// 662.228 us; speedup vs baseline: 1.0741x; 1.0023x over previous
//
#include <hip/hip_runtime.h>

// ---------------- Kernel 0: segment offsets + fused mask bias ----------------
__global__ void k_offsets(const int* __restrict__ batch, const int* __restrict__ cdr,
                          const int* __restrict__ ifm, const float* __restrict__ cdr_bias,
                          const float* __restrict__ iface_bias,
                          int* __restrict__ start, float* __restrict__ mbias,
                          int N, int B) {
    int i = blockIdx.x * blockDim.x + threadIdx.x;
    if (i >= N) return;
    mbias[i] = cdr_bias[0] * (float)cdr[i] + iface_bias[0] * (float)ifm[i];
    int b = batch[i];
    if (i == 0) {
        for (int g = 0; g <= b; ++g) start[g] = 0;
    } else {
        int pb = batch[i - 1];
        for (int g = pb + 1; g <= b; ++g) start[g] = i;
    }
    if (i == N - 1) {
        for (int g = b + 1; g <= B; ++g) start[g] = N;
    }
}

// ---------------- Kernel P: slice-partial mean/max pooling (deterministic) ----------------
// 4 slices per graph -> 4096 blocks. Wave w owns rows qs+w, qs+w+4, ... with a 4-deep
// ROLLING pipeline (refill each row slot right after consuming it) so ~4 KB/wave of
// loads stay in flight continuously (the old version serialized 4-row batches:
// load4 -> consume4 -> load4, exposing full HBM latency per batch). NO atomics.
__global__ __launch_bounds__(256) void k_pool(
    const float* __restrict__ h, const int* __restrict__ start,
    float* __restrict__ psum, float* __restrict__ pmax)
{
    const int g = blockIdx.x >> 2;
    const int sl = blockIdx.x & 3;
    const int tid = threadIdx.x;
    const int w = tid >> 6;
    const int l = tid & 63;
    const int s = start[g], e = start[g + 1];
    const int len = e - s;
    const int qs = s + (len * sl) / 4;
    const int qe = s + (len * (sl + 1)) / 4;

    float4 sm = make_float4(0.f, 0.f, 0.f, 0.f);
    float4 mx = make_float4(-INFINITY, -INFINITY, -INFINITY, -INFINITY);

    #define ACC(v) do { \
        sm.x += (v).x; sm.y += (v).y; sm.z += (v).z; sm.w += (v).w; \
        mx.x = fmaxf(mx.x, (v).x); mx.y = fmaxf(mx.y, (v).y); \
        mx.z = fmaxf(mx.z, (v).z); mx.w = fmaxf(mx.w, (v).w); } while (0)

    int n = qs + w;
    if (n + 12 < qe) {
        float4 f0 = *(const float4*)(h + (size_t)(n)      * 256 + l * 4);
        float4 f1 = *(const float4*)(h + (size_t)(n + 4)  * 256 + l * 4);
        float4 f2 = *(const float4*)(h + (size_t)(n + 8)  * 256 + l * 4);
        float4 f3 = *(const float4*)(h + (size_t)(n + 12) * 256 + l * 4);
        for (; n + 28 < qe; n += 16) {
            ACC(f0); f0 = *(const float4*)(h + (size_t)(n + 16) * 256 + l * 4);
            ACC(f1); f1 = *(const float4*)(h + (size_t)(n + 20) * 256 + l * 4);
            ACC(f2); f2 = *(const float4*)(h + (size_t)(n + 24) * 256 + l * 4);
            ACC(f3); f3 = *(const float4*)(h + (size_t)(n + 28) * 256 + l * 4);
        }
        ACC(f0); ACC(f1); ACC(f2); ACC(f3);
        n += 16;
    }
    for (; n < qe; n += 4) {
        const float4 a = *(const float4*)(h + (size_t)n * 256 + l * 4);
        ACC(a);
    }
    #undef ACC

    __shared__ __align__(16) float PS[4][256];
    __shared__ __align__(16) float PM[4][256];
    *(float4*)(&PS[w][l * 4]) = sm;
    *(float4*)(&PM[w][l * 4]) = mx;
    __syncthreads();
    const int d = tid;
    const float sum = (PS[0][d] + PS[1][d]) + (PS[2][d] + PS[3][d]);
    const float mxv = fmaxf(fmaxf(PM[0][d], PM[1][d]), fmaxf(PM[2][d], PM[3][d]));
    psum[(size_t)blockIdx.x * 256 + d] = sum;
    pmax[(size_t)blockIdx.x * 256 + d] = mxv;
}

// ---------------- Kernel Q: partials -> mean/max -> q -> LN -> folded w_eff ----------------
// one block per graph, 256 threads; thread d owns dim d.
// w_eff is stored FOLDED: w_eff[g,h,j] = (sum_r Wk[h*32+r,j]*QL[h*32+r]) * scale * ln_kv_w[j]
// so k_attn computes logits on RAW x (const(g,h)=sum we*lnb is softmax-invariant, dropped).
__global__ __launch_bounds__(256) void k_q(
    const float* __restrict__ psum, const float* __restrict__ pmax,
    const int* __restrict__ start,
    const float* __restrict__ Wq, const float* __restrict__ Wk,
    const float* __restrict__ ln_q_w, const float* __restrict__ ln_q_b,
    const float* __restrict__ ln_kv_w, const float* __restrict__ logit_scale,
    float* __restrict__ mean_raw, float* __restrict__ w_eff)
{
    const int g = blockIdx.x;
    const int d = threadIdx.x;
    const int s = start[g], e = start[g + 1];

    float sum = 0.f, mxv = -INFINITY;
    #pragma unroll
    for (int sl = 0; sl < 4; ++sl) {
        sum += psum[((size_t)g * 4 + sl) * 256 + d];
        mxv = fmaxf(mxv, pmax[((size_t)g * 4 + sl) * 256 + d]);
    }
    const float mean = sum / (float)(e - s);
    mean_raw[(size_t)g * 256 + d] = mean;

    __shared__ __align__(16) float X[512];   // [mean | max]
    __shared__ float QL[256];
    __shared__ float rs[4], rq[4];
    X[d] = mean;
    X[256 + d] = mxv;
    __syncthreads();

    // q[d] = sum_j X[j] * Wq[d,j]   (Wq is (256,512) row-major)
    float q = 0.f;
    const float* wqr = Wq + (size_t)d * 512;
    #pragma unroll 8
    for (int j = 0; j < 512; j += 4) {
        float4 w4 = *(const float4*)(wqr + j);
        q += w4.x * X[j] + w4.y * X[j + 1] + w4.z * X[j + 2] + w4.w * X[j + 3];
    }
    // block LayerNorm over the 256 q values
    float s1 = q, s2 = q * q;
    #pragma unroll
    for (int off = 1; off < 64; off <<= 1) {
        s1 += __shfl_xor(s1, off);
        s2 += __shfl_xor(s2, off);
    }
    if ((d & 63) == 0) { rs[d >> 6] = s1; rq[d >> 6] = s2; }
    __syncthreads();
    const float t1 = rs[0] + rs[1] + rs[2] + rs[3];
    const float t2 = rq[0] + rq[1] + rq[2] + rq[3];
    const float mu = t1 * (1.f / 256.f);
    const float var = t2 * (1.f / 256.f) - mu * mu;
    const float rstd = rsqrtf(var + 1e-5f);
    QL[d] = (q - mu) * rstd * ln_q_w[d] + ln_q_b[d];
    __syncthreads();

    const float scale = logit_scale[0] * 0.17677669529663687f; // 1/sqrt(32)
    const float fold = scale * ln_kv_w[d];
    #pragma unroll
    for (int hh = 0; hh < 8; ++hh) {
        float a = 0.f;
        #pragma unroll 8
        for (int r = 0; r < 32; ++r) {
            a += Wk[(size_t)(hh * 32 + r) * 256 + d] * QL[hh * 32 + r];
        }
        w_eff[((size_t)g * 8 + hh) * 256 + d] = a * fold;
    }
}

// ---------------- Kernel B: logits on raw x + online segment softmax + u ----------------
// one block per graph, 4 waves; wave w handles nodes s+w, s+w+4, ... (depth-2 rolling
// prefetch x0/x1). lane layout: hh = l>>3 (head), p = l&7 (32-wide j-chunk).
// LN stats s1/s2 are computed from the float4 the lane LOADED (each lane owns 4 unique
// elements -> 7 VALU inst vs 64 on the chunk), reduced xor(8,16,32) [across hh] then
// jointly with the per-head dot via xor(1,2,4) [across p]. The early stats reduce
// overlaps the LDS write->fence->read->dot path.
// u accumulates raw x with weight e*rstd; lnw/lnb correction applied in the epilogue:
//   sum_n e_n * h_ln[n,j] = lnw_j*(U[j] - Sw) + lnb_j*Z,  Sw = sum e*rstd*mu, Z = sum e
// NOTE: plain __launch_bounds__(256) — a (256,4) min-waves hint capped VGPR at 64 and
// spilled u[32]/hv[32] to scratch (418 MB WRITE_SIZE, 2.3x slower). Do not re-add.
__global__ __launch_bounds__(256) void k_attn(
    const float* __restrict__ h, const int* __restrict__ start,
    const float* __restrict__ mbias,
    const float* __restrict__ ln_w, const float* __restrict__ ln_b,
    const float* __restrict__ w_eff,
    float* __restrict__ u_norm)
{
    const int g = blockIdx.x;
    const int tid = threadIdx.x;
    const int w = tid >> 6;
    const int l = tid & 63;
    const int hh = l >> 3;
    const int p = l & 7;
    const int s = start[g], e = start[g + 1];

    // folded key weights A for (head hh, chunk p)
    float we[32];
    {
        const float* wp = w_eff + ((size_t)g * 8 + hh) * 256 + p * 32;
        #pragma unroll
        for (int r = 0; r < 8; ++r) {
            float4 t = *(const float4*)(wp + r * 4);
            we[4 * r + 0] = t.x; we[4 * r + 1] = t.y; we[4 * r + 2] = t.z; we[4 * r + 3] = t.w;
        }
    }
    // s1h = sum_j A[hh][j]  (uniform across the 8 lanes of a head after reduce)
    float s1h = 0.f;
    #pragma unroll
    for (int r = 0; r < 32; ++r) s1h += we[r];
    s1h += __shfl_xor(s1h, 1);
    s1h += __shfl_xor(s1h, 2);
    s1h += __shfl_xor(s1h, 4);

    float m = -INFINITY, z = 0.f, sw = 0.f;
    float u[32];
    #pragma unroll
    for (int r = 0; r < 32; ++r) u[r] = 0.f;

    // padded row buffer: 32-float chunk c lives at float offset c*36
    __shared__ __align__(16) float hbuf[4][288];
    __shared__ __align__(16) float UF[4][8][264];   // padded: kills conflicts on p*32 writes
    __shared__ float MW[4][8], ZW[4][8], SW[4][8], FG[4][8], IZ[8], SG[8];

    const int wofs = l * 4 + ((l >> 3) << 2); // padded offset of j = l*4
    const int rofs = p * 36;                  // padded base of chunk p

    int n = s + w;
    float4 x0 = make_float4(0.f, 0.f, 0.f, 0.f);
    float4 x1 = x0;
    float b0 = 0.f, b1 = 0.f;
    if (n < e)     { x0 = *(const float4*)(h + (size_t)n * 256 + l * 4);       b0 = mbias[n]; }
    if (n + 4 < e) { x1 = *(const float4*)(h + (size_t)(n + 4) * 256 + l * 4); b1 = mbias[n + 4]; }

    while (n < e) {
        const float4 xc = x0;
        const float bc = b0;
        x0 = x1; b0 = b1;
        if (n + 8 < e) {                       // depth-2 rolling prefetch
            x1 = *(const float4*)(h + (size_t)(n + 8) * 256 + l * 4);
            b1 = mbias[n + 8];
        }

        // lane-local LN stats from the 4 elements this lane LOADED (unique coverage),
        // reduced across hh early so the chain overlaps the LDS round-trip below.
        float s1 = (xc.x + xc.y) + (xc.z + xc.w);
        float s2 = xc.x * xc.x;
        s2 = fmaf(xc.y, xc.y, s2);
        s2 = fmaf(xc.z, xc.z, s2);
        s2 = fmaf(xc.w, xc.w, s2);
        s1 += __shfl_xor(s1, 8);  s2 += __shfl_xor(s2, 8);
        s1 += __shfl_xor(s1, 16); s2 += __shfl_xor(s2, 16);
        s1 += __shfl_xor(s1, 32); s2 += __shfl_xor(s2, 32);

        *(float4*)(&hbuf[w][wofs]) = xc;       // RAW x (no LN yet)
        asm volatile("s_waitcnt lgkmcnt(0)" ::: "memory");

        float hv[32];
        #pragma unroll
        for (int r = 0; r < 8; ++r) {
            float4 t = *(const float4*)(&hbuf[w][rofs + r * 4]);
            hv[4 * r + 0] = t.x; hv[4 * r + 1] = t.y; hv[4 * r + 2] = t.z; hv[4 * r + 3] = t.w;
        }
        float dt = 0.f;
        #pragma unroll
        for (int r = 0; r < 32; ++r) dt = fmaf(hv[r], we[r], dt);
        // joint 3-level reduce across p: completes s1/s2 (full row) and dt (per head)
        #pragma unroll
        for (int off = 1; off < 8; off <<= 1) {
            s1 += __shfl_xor(s1, off);
            s2 += __shfl_xor(s2, off);
            dt += __shfl_xor(dt, off);
        }
        const float mu = s1 * (1.f / 256.f);
        const float var = s2 * (1.f / 256.f) - mu * mu;
        const float rstd = rsqrtf(var + 1e-5f);
        const float lv = rstd * (dt - mu * s1h) + bc;

        const float nm = fmaxf(m, lv);
        const float ee = __expf(lv - nm);
        const float c = ee * rstd;
        if (__any(lv > m)) {                   // max moved: rescale path
            const float a = __expf(m - nm);    // exp(-inf)=0 on first node
            z = z * a + ee;
            sw = sw * a + c * mu;
            #pragma unroll
            for (int r = 0; r < 32; ++r) u[r] = u[r] * a + c * hv[r];
            m = nm;
        } else {                               // common path: no rescale, 1 FMA per elem
            z += ee;
            sw += c * mu;
            #pragma unroll
            for (int r = 0; r < 32; ++r) u[r] = fmaf(c, hv[r], u[r]);
        }
        n += 4;
    }

    if (p == 0) { MW[w][hh] = m; ZW[w][hh] = z; SW[w][hh] = sw; }
    #pragma unroll
    for (int r = 0; r < 8; ++r) {
        float4 t = make_float4(u[4 * r], u[4 * r + 1], u[4 * r + 2], u[4 * r + 3]);
        *(float4*)(&UF[w][hh][p * 32 + r * 4]) = t;
    }
    __syncthreads();

    if (tid < 8) {
        const float mg = fmaxf(fmaxf(MW[0][tid], MW[1][tid]),
                               fmaxf(MW[2][tid], MW[3][tid]));
        float zg = 0.f, sg = 0.f;
        #pragma unroll
        for (int ww = 0; ww < 4; ++ww) {
            const float f = __expf(MW[ww][tid] - mg);  // empty wave: exp(-inf)=0
            FG[ww][tid] = f;
            zg += ZW[ww][tid] * f;
            sg += SW[ww][tid] * f;
        }
        IZ[tid] = 1.f / zg;
        SG[tid] = sg;
    }
    __syncthreads();

    const float lwj = ln_w[tid], lbj = ln_b[tid];
    #pragma unroll
    for (int h2 = 0; h2 < 8; ++h2) {
        const float Uv = UF[0][h2][tid] * FG[0][h2] + UF[1][h2][tid] * FG[1][h2]
                       + UF[2][h2][tid] * FG[2][h2] + UF[3][h2][tid] * FG[3][h2];
        u_norm[(size_t)g * 2048 + h2 * 256 + tid] = (Uv - SG[h2]) * IZ[h2] * lwj + lbj;
    }
}

// ---------------- Kernel C: g = Wv . u_norm (head-selected), out = Wout.g + 0.2*Wres.mean ----------------
// one graph per block (1024 blocks -> 4 blocks/CU; weights are L2-resident)
__global__ __launch_bounds__(256) void k_out(
    const float* __restrict__ u_norm, const float* __restrict__ mean_raw,
    const float* __restrict__ Wv, const float* __restrict__ Wout,
    const float* __restrict__ Wres, float* __restrict__ out)
{
    const int d = threadIdx.x;
    const int g = blockIdx.x;
    __shared__ __align__(16) float UN[8][256];  // 8 KB
    __shared__ __align__(16) float MR[256];
    __shared__ __align__(16) float GF[256];

    const float4* up = (const float4*)(u_norm + (size_t)g * 2048);
    ((float4*)UN)[d] = up[d];
    ((float4*)UN)[256 + d] = up[256 + d];
    if (d < 64) ((float4*)MR)[d] = ((const float4*)(mean_raw + (size_t)g * 256))[d];
    __syncthreads();

    const int hh = d >> 5;
    float acc = 0.f;
    const float* wvr = Wv + (size_t)d * 256;
    #pragma unroll 8
    for (int j = 0; j < 256; j += 4) {
        const float4 wv = *(const float4*)(wvr + j);
        const float4 uv = *(const float4*)(&UN[hh][j]);
        acc += wv.x * uv.x + wv.y * uv.y + wv.z * uv.z + wv.w * uv.w;
    }
    GF[d] = acc;
    __syncthreads();

    float oo = 0.f, rr = 0.f;
    const float* wor = Wout + (size_t)d * 256;
    const float* wrr = Wres + (size_t)d * 256;
    #pragma unroll 8
    for (int j = 0; j < 256; j += 4) {
        const float4 wo = *(const float4*)(wor + j);
        const float4 wq = *(const float4*)(wrr + j);
        const float4 gf = *(const float4*)(&GF[j]);
        const float4 mr = *(const float4*)(&MR[j]);
        oo += wo.x * gf.x + wo.y * gf.y + wo.z * gf.z + wo.w * gf.w;
        rr += wq.x * mr.x + wq.y * mr.y + wq.z * mr.z + wq.w * mr.w;
    }
    out[(size_t)g * 256 + d] = oo + 0.2f * rr;
}

// ---------------- launch ----------------
extern "C" void kernel_launch(void* const* d_in, const int* in_sizes, int n_in,
                              void* d_out, int out_size, void* d_ws, size_t ws_size,
                              hipStream_t stream)
{
    const float* h        = (const float*)d_in[0];
    const int*   batch    = (const int*)d_in[1];
    const int*   cdr      = (const int*)d_in[2];   // bool mask arrives as int32
    const int*   ifm      = (const int*)d_in[3];   // bool mask arrives as int32
    const float* ln_kv_w  = (const float*)d_in[4];
    const float* ln_kv_b  = (const float*)d_in[5];
    const float* ln_q_w   = (const float*)d_in[6];
    const float* ln_q_b   = (const float*)d_in[7];
    const float* Wk       = (const float*)d_in[8];
    const float* Wv       = (const float*)d_in[9];
    const float* Wq       = (const float*)d_in[10];
    const float* Wres     = (const float*)d_in[11];
    const float* Wout     = (const float*)d_in[12];
    const float* cdr_b    = (const float*)d_in[13];
    const float* if_b     = (const float*)d_in[14];
    const float* lsc      = (const float*)d_in[15];

    const int N = in_sizes[0] / 256;   // 262144
    const int B = out_size / 256;      // 1024

    int*   start    = (int*)d_ws;                         // (B+1) ints (8 KB reserved)
    float* mean_raw = (float*)((char*)d_ws + 8192);       // B*256 floats (1 MB)
    float* w_eff    = mean_raw + (size_t)B * 256;         // B*8*256 floats (8 MB)
    float* u_norm   = w_eff + (size_t)B * 2048;           // B*8*256 floats (8 MB)
    float* psum     = u_norm + (size_t)B * 2048;          // 4B*256 floats (4 MB)
    float* pmax     = psum + (size_t)B * 1024;            // 4B*256 floats (4 MB)
    float* mbias    = pmax + (size_t)B * 1024;            // N floats (1 MB)

    k_offsets<<<(N + 255) / 256, 256, 0, stream>>>(batch, cdr, ifm, cdr_b, if_b,
                                                   start, mbias, N, B);
    k_pool<<<B * 4, 256, 0, stream>>>(h, start, psum, pmax);
    k_q<<<B, 256, 0, stream>>>(psum, pmax, start, Wq, Wk, ln_q_w, ln_q_b, ln_kv_w,
                               lsc, mean_raw, w_eff);
    k_attn<<<B, 256, 0, stream>>>(h, start, mbias, ln_kv_w, ln_kv_b, w_eff, u_norm);
    k_out<<<B, 256, 0, stream>>>(u_norm, mean_raw, Wv, Wout, Wres, (float*)d_out);
}

// Round 7
// 652.828 us; speedup vs baseline: 1.0895x; 1.0144x over previous
//
#include <hip/hip_runtime.h>

// ---------------- Kernel 0: segment offsets + fused mask bias ----------------
__global__ void k_offsets(const int* __restrict__ batch, const int* __restrict__ cdr,
                          const int* __restrict__ ifm, const float* __restrict__ cdr_bias,
                          const float* __restrict__ iface_bias,
                          int* __restrict__ start, float* __restrict__ mbias,
                          int N, int B) {
    int i = blockIdx.x * blockDim.x + threadIdx.x;
    if (i >= N) return;
    mbias[i] = cdr_bias[0] * (float)cdr[i] + iface_bias[0] * (float)ifm[i];
    int b = batch[i];
    if (i == 0) {
        for (int g = 0; g <= b; ++g) start[g] = 0;
    } else {
        int pb = batch[i - 1];
        for (int g = pb + 1; g <= b; ++g) start[g] = i;
    }
    if (i == N - 1) {
        for (int g = b + 1; g <= B; ++g) start[g] = N;
    }
}

// ---------------- Kernel P: slice-partial mean/max pooling + per-row LN stats ----------------
// 4 slices per graph -> 4096 blocks, rolling 4-deep pipeline. NEW: since this kernel
// already reads every row of h, it also computes each row's LayerNorm (mu, rstd) via a
// 6-level butterfly (12 DS ops/row — free here: each wave moves only ~16 KB total, so
// the DS/VALU pipes are idle) and stores stat[n]. This removes 6 shuffles + the
// var/rsqrt chain from k_attn's per-node critical path. NO atomics (deterministic).
__global__ __launch_bounds__(256) void k_pool(
    const float* __restrict__ h, const int* __restrict__ start,
    float* __restrict__ psum, float* __restrict__ pmax, float2* __restrict__ stat)
{
    const int g = blockIdx.x >> 2;
    const int sl = blockIdx.x & 3;
    const int tid = threadIdx.x;
    const int w = tid >> 6;
    const int l = tid & 63;
    const int s = start[g], e = start[g + 1];
    const int len = e - s;
    const int qs = s + (len * sl) / 4;
    const int qe = s + (len * (sl + 1)) / 4;

    float4 sm = make_float4(0.f, 0.f, 0.f, 0.f);
    float4 mx = make_float4(-INFINITY, -INFINITY, -INFINITY, -INFINITY);

    #define PROC(v, rowidx) do { \
        sm.x += (v).x; sm.y += (v).y; sm.z += (v).z; sm.w += (v).w; \
        mx.x = fmaxf(mx.x, (v).x); mx.y = fmaxf(mx.y, (v).y); \
        mx.z = fmaxf(mx.z, (v).z); mx.w = fmaxf(mx.w, (v).w); \
        float s1_ = ((v).x + (v).y) + ((v).z + (v).w); \
        float s2_ = fmaf((v).x, (v).x, fmaf((v).y, (v).y, fmaf((v).z, (v).z, (v).w * (v).w))); \
        s1_ += __shfl_xor(s1_, 1);  s2_ += __shfl_xor(s2_, 1); \
        s1_ += __shfl_xor(s1_, 2);  s2_ += __shfl_xor(s2_, 2); \
        s1_ += __shfl_xor(s1_, 4);  s2_ += __shfl_xor(s2_, 4); \
        s1_ += __shfl_xor(s1_, 8);  s2_ += __shfl_xor(s2_, 8); \
        s1_ += __shfl_xor(s1_, 16); s2_ += __shfl_xor(s2_, 16); \
        s1_ += __shfl_xor(s1_, 32); s2_ += __shfl_xor(s2_, 32); \
        if (l == 0) { \
            const float mu_ = s1_ * (1.f / 256.f); \
            const float var_ = s2_ * (1.f / 256.f) - mu_ * mu_; \
            stat[rowidx] = make_float2(mu_, rsqrtf(var_ + 1e-5f)); \
        } } while (0)

    int n = qs + w;
    if (n + 12 < qe) {
        float4 f0 = *(const float4*)(h + (size_t)(n)      * 256 + l * 4);
        float4 f1 = *(const float4*)(h + (size_t)(n + 4)  * 256 + l * 4);
        float4 f2 = *(const float4*)(h + (size_t)(n + 8)  * 256 + l * 4);
        float4 f3 = *(const float4*)(h + (size_t)(n + 12) * 256 + l * 4);
        for (; n + 28 < qe; n += 16) {
            PROC(f0, n);      f0 = *(const float4*)(h + (size_t)(n + 16) * 256 + l * 4);
            PROC(f1, n + 4);  f1 = *(const float4*)(h + (size_t)(n + 20) * 256 + l * 4);
            PROC(f2, n + 8);  f2 = *(const float4*)(h + (size_t)(n + 24) * 256 + l * 4);
            PROC(f3, n + 12); f3 = *(const float4*)(h + (size_t)(n + 28) * 256 + l * 4);
        }
        PROC(f0, n); PROC(f1, n + 4); PROC(f2, n + 8); PROC(f3, n + 12);
        n += 16;
    }
    for (; n < qe; n += 4) {
        const float4 a = *(const float4*)(h + (size_t)n * 256 + l * 4);
        PROC(a, n);
    }
    #undef PROC

    __shared__ __align__(16) float PS[4][256];
    __shared__ __align__(16) float PM[4][256];
    *(float4*)(&PS[w][l * 4]) = sm;
    *(float4*)(&PM[w][l * 4]) = mx;
    __syncthreads();
    const int d = tid;
    const float sum = (PS[0][d] + PS[1][d]) + (PS[2][d] + PS[3][d]);
    const float mxv = fmaxf(fmaxf(PM[0][d], PM[1][d]), fmaxf(PM[2][d], PM[3][d]));
    psum[(size_t)blockIdx.x * 256 + d] = sum;
    pmax[(size_t)blockIdx.x * 256 + d] = mxv;
}

// ---------------- Kernel Q: partials -> mean/max -> q -> LN -> folded w_eff ----------------
// one block per graph, 256 threads; thread d owns dim d.
// w_eff is stored FOLDED: w_eff[g,h,j] = (sum_r Wk[h*32+r,j]*QL[h*32+r]) * scale * ln_kv_w[j]
// so k_attn computes logits on RAW x (const(g,h)=sum we*lnb is softmax-invariant, dropped).
__global__ __launch_bounds__(256) void k_q(
    const float* __restrict__ psum, const float* __restrict__ pmax,
    const int* __restrict__ start,
    const float* __restrict__ Wq, const float* __restrict__ Wk,
    const float* __restrict__ ln_q_w, const float* __restrict__ ln_q_b,
    const float* __restrict__ ln_kv_w, const float* __restrict__ logit_scale,
    float* __restrict__ mean_raw, float* __restrict__ w_eff)
{
    const int g = blockIdx.x;
    const int d = threadIdx.x;
    const int s = start[g], e = start[g + 1];

    float sum = 0.f, mxv = -INFINITY;
    #pragma unroll
    for (int sl = 0; sl < 4; ++sl) {
        sum += psum[((size_t)g * 4 + sl) * 256 + d];
        mxv = fmaxf(mxv, pmax[((size_t)g * 4 + sl) * 256 + d]);
    }
    const float mean = sum / (float)(e - s);
    mean_raw[(size_t)g * 256 + d] = mean;

    __shared__ __align__(16) float X[512];   // [mean | max]
    __shared__ float QL[256];
    __shared__ float rs[4], rq[4];
    X[d] = mean;
    X[256 + d] = mxv;
    __syncthreads();

    // q[d] = sum_j X[j] * Wq[d,j]   (Wq is (256,512) row-major)
    float q = 0.f;
    const float* wqr = Wq + (size_t)d * 512;
    #pragma unroll 8
    for (int j = 0; j < 512; j += 4) {
        float4 w4 = *(const float4*)(wqr + j);
        q += w4.x * X[j] + w4.y * X[j + 1] + w4.z * X[j + 2] + w4.w * X[j + 3];
    }
    // block LayerNorm over the 256 q values
    float s1 = q, s2 = q * q;
    #pragma unroll
    for (int off = 1; off < 64; off <<= 1) {
        s1 += __shfl_xor(s1, off);
        s2 += __shfl_xor(s2, off);
    }
    if ((d & 63) == 0) { rs[d >> 6] = s1; rq[d >> 6] = s2; }
    __syncthreads();
    const float t1 = rs[0] + rs[1] + rs[2] + rs[3];
    const float t2 = rq[0] + rq[1] + rq[2] + rq[3];
    const float mu = t1 * (1.f / 256.f);
    const float var = t2 * (1.f / 256.f) - mu * mu;
    const float rstd = rsqrtf(var + 1e-5f);
    QL[d] = (q - mu) * rstd * ln_q_w[d] + ln_q_b[d];
    __syncthreads();

    const float scale = logit_scale[0] * 0.17677669529663687f; // 1/sqrt(32)
    const float fold = scale * ln_kv_w[d];
    #pragma unroll
    for (int hh = 0; hh < 8; ++hh) {
        float a = 0.f;
        #pragma unroll 8
        for (int r = 0; r < 32; ++r) {
            a += Wk[(size_t)(hh * 32 + r) * 256 + d] * QL[hh * 32 + r];
        }
        w_eff[((size_t)g * 8 + hh) * 256 + d] = a * fold;
    }
}

// ---------------- Kernel B: logits on raw x + online segment softmax + u ----------------
// one block per graph, 4 waves; wave w handles nodes s+w, s+w+4, ... (depth-2 rolling
// prefetch of x + mbias + stat). lane layout: hh = l>>3 (head), p = l&7 (32-wide chunk).
// Per node now: LDS write -> fence -> 8 b128 reads -> 4-acc dot -> 3 shuffles -> lv.
// (mu, rstd) are PRECOMPUTED in k_pool (stat[n]); DS ops/node 24 -> 12, and the
// var/rsqrt chain is gone from the loop.
// u accumulates raw x with weight e*rstd; lnw/lnb correction applied in the epilogue:
//   sum_n e_n * h_ln[n,j] = lnw_j*(U[j] - Sw) + lnb_j*Z,  Sw = sum e*rstd*mu, Z = sum e
// NOTE: plain __launch_bounds__(256) — a (256,4) min-waves hint capped VGPR at 64 and
// spilled u[32]/hv[32] to scratch (418 MB WRITE_SIZE, 2.3x slower). Do not re-add.
__global__ __launch_bounds__(256) void k_attn(
    const float* __restrict__ h, const int* __restrict__ start,
    const float* __restrict__ mbias, const float2* __restrict__ stat,
    const float* __restrict__ ln_w, const float* __restrict__ ln_b,
    const float* __restrict__ w_eff,
    float* __restrict__ u_norm)
{
    const int g = blockIdx.x;
    const int tid = threadIdx.x;
    const int w = tid >> 6;
    const int l = tid & 63;
    const int hh = l >> 3;
    const int p = l & 7;
    const int s = start[g], e = start[g + 1];

    // folded key weights A for (head hh, chunk p)
    float we[32];
    {
        const float* wp = w_eff + ((size_t)g * 8 + hh) * 256 + p * 32;
        #pragma unroll
        for (int r = 0; r < 8; ++r) {
            float4 t = *(const float4*)(wp + r * 4);
            we[4 * r + 0] = t.x; we[4 * r + 1] = t.y; we[4 * r + 2] = t.z; we[4 * r + 3] = t.w;
        }
    }
    // s1h = sum_j A[hh][j]  (uniform across the 8 lanes of a head after reduce)
    float s1h = 0.f;
    #pragma unroll
    for (int r = 0; r < 32; ++r) s1h += we[r];
    s1h += __shfl_xor(s1h, 1);
    s1h += __shfl_xor(s1h, 2);
    s1h += __shfl_xor(s1h, 4);

    float m = -INFINITY, z = 0.f, sw = 0.f;
    float u[32];
    #pragma unroll
    for (int r = 0; r < 32; ++r) u[r] = 0.f;

    // padded row buffer: 32-float chunk c lives at float offset c*36
    __shared__ __align__(16) float hbuf[4][288];
    __shared__ __align__(16) float UF[4][8][264];   // padded: kills conflicts on p*32 writes
    __shared__ float MW[4][8], ZW[4][8], SW[4][8], FG[4][8], IZ[8], SG[8];

    const int wofs = l * 4 + ((l >> 3) << 2); // padded offset of j = l*4
    const int rofs = p * 36;                  // padded base of chunk p

    int n = s + w;
    float4 x0 = make_float4(0.f, 0.f, 0.f, 0.f);
    float4 x1 = x0;
    float b0 = 0.f, b1 = 0.f;
    float2 t0 = make_float2(0.f, 1.f), t1 = t0;
    if (n < e)     { x0 = *(const float4*)(h + (size_t)n * 256 + l * 4);
                     b0 = mbias[n];     t0 = stat[n]; }
    if (n + 4 < e) { x1 = *(const float4*)(h + (size_t)(n + 4) * 256 + l * 4);
                     b1 = mbias[n + 4]; t1 = stat[n + 4]; }

    while (n < e) {
        const float4 xc = x0;
        const float bc = b0;
        const float2 tc = t0;
        x0 = x1; b0 = b1; t0 = t1;
        if (n + 8 < e) {                       // depth-2 rolling prefetch
            x1 = *(const float4*)(h + (size_t)(n + 8) * 256 + l * 4);
            b1 = mbias[n + 8];
            t1 = stat[n + 8];
        }

        *(float4*)(&hbuf[w][wofs]) = xc;       // RAW x (no LN yet)
        asm volatile("s_waitcnt lgkmcnt(0)" ::: "memory");

        float hv[32];
        #pragma unroll
        for (int r = 0; r < 8; ++r) {
            float4 t = *(const float4*)(&hbuf[w][rofs + r * 4]);
            hv[4 * r + 0] = t.x; hv[4 * r + 1] = t.y; hv[4 * r + 2] = t.z; hv[4 * r + 3] = t.w;
        }
        // 4-accumulator dot (8-deep chains instead of 32-deep)
        float d0 = 0.f, d1 = 0.f, d2 = 0.f, d3 = 0.f;
        #pragma unroll
        for (int r = 0; r < 8; ++r) {
            d0 = fmaf(hv[4 * r + 0], we[4 * r + 0], d0);
            d1 = fmaf(hv[4 * r + 1], we[4 * r + 1], d1);
            d2 = fmaf(hv[4 * r + 2], we[4 * r + 2], d2);
            d3 = fmaf(hv[4 * r + 3], we[4 * r + 3], d3);
        }
        float dt = (d0 + d1) + (d2 + d3);
        dt += __shfl_xor(dt, 1);
        dt += __shfl_xor(dt, 2);
        dt += __shfl_xor(dt, 4);               // 8 lanes of the head hold the dot

        const float mu = tc.x, rstd = tc.y;
        const float lv = fmaf(rstd, dt - mu * s1h, bc);

        const float nm = fmaxf(m, lv);
        const float ee = __expf(lv - nm);
        const float c = ee * rstd;
        if (__any(lv > m)) {                   // max moved: rescale path
            const float a = __expf(m - nm);    // exp(-inf)=0 on first node
            z = z * a + ee;
            sw = sw * a + c * mu;
            #pragma unroll
            for (int r = 0; r < 32; ++r) u[r] = u[r] * a + c * hv[r];
            m = nm;
        } else {                               // common path: no rescale, 1 FMA per elem
            z += ee;
            sw += c * mu;
            #pragma unroll
            for (int r = 0; r < 32; ++r) u[r] = fmaf(c, hv[r], u[r]);
        }
        n += 4;
    }

    if (p == 0) { MW[w][hh] = m; ZW[w][hh] = z; SW[w][hh] = sw; }
    #pragma unroll
    for (int r = 0; r < 8; ++r) {
        float4 t = make_float4(u[4 * r], u[4 * r + 1], u[4 * r + 2], u[4 * r + 3]);
        *(float4*)(&UF[w][hh][p * 32 + r * 4]) = t;
    }
    __syncthreads();

    if (tid < 8) {
        const float mg = fmaxf(fmaxf(MW[0][tid], MW[1][tid]),
                               fmaxf(MW[2][tid], MW[3][tid]));
        float zg = 0.f, sg = 0.f;
        #pragma unroll
        for (int ww = 0; ww < 4; ++ww) {
            const float f = __expf(MW[ww][tid] - mg);  // empty wave: exp(-inf)=0
            FG[ww][tid] = f;
            zg += ZW[ww][tid] * f;
            sg += SW[ww][tid] * f;
        }
        IZ[tid] = 1.f / zg;
        SG[tid] = sg;
    }
    __syncthreads();

    const float lwj = ln_w[tid], lbj = ln_b[tid];
    #pragma unroll
    for (int h2 = 0; h2 < 8; ++h2) {
        const float Uv = UF[0][h2][tid] * FG[0][h2] + UF[1][h2][tid] * FG[1][h2]
                       + UF[2][h2][tid] * FG[2][h2] + UF[3][h2][tid] * FG[3][h2];
        u_norm[(size_t)g * 2048 + h2 * 256 + tid] = (Uv - SG[h2]) * IZ[h2] * lwj + lbj;
    }
}

// ---------------- Kernel C: g = Wv . u_norm (head-selected), out = Wout.g + 0.2*Wres.mean ----------------
// one graph per block (1024 blocks -> 4 blocks/CU; weights are L2-resident)
__global__ __launch_bounds__(256) void k_out(
    const float* __restrict__ u_norm, const float* __restrict__ mean_raw,
    const float* __restrict__ Wv, const float* __restrict__ Wout,
    const float* __restrict__ Wres, float* __restrict__ out)
{
    const int d = threadIdx.x;
    const int g = blockIdx.x;
    __shared__ __align__(16) float UN[8][256];  // 8 KB
    __shared__ __align__(16) float MR[256];
    __shared__ __align__(16) float GF[256];

    const float4* up = (const float4*)(u_norm + (size_t)g * 2048);
    ((float4*)UN)[d] = up[d];
    ((float4*)UN)[256 + d] = up[256 + d];
    if (d < 64) ((float4*)MR)[d] = ((const float4*)(mean_raw + (size_t)g * 256))[d];
    __syncthreads();

    const int hh = d >> 5;
    float acc = 0.f;
    const float* wvr = Wv + (size_t)d * 256;
    #pragma unroll 8
    for (int j = 0; j < 256; j += 4) {
        const float4 wv = *(const float4*)(wvr + j);
        const float4 uv = *(const float4*)(&UN[hh][j]);
        acc += wv.x * uv.x + wv.y * uv.y + wv.z * uv.z + wv.w * uv.w;
    }
    GF[d] = acc;
    __syncthreads();

    float oo = 0.f, rr = 0.f;
    const float* wor = Wout + (size_t)d * 256;
    const float* wrr = Wres + (size_t)d * 256;
    #pragma unroll 8
    for (int j = 0; j < 256; j += 4) {
        const float4 wo = *(const float4*)(wor + j);
        const float4 wq = *(const float4*)(wrr + j);
        const float4 gf = *(const float4*)(&GF[j]);
        const float4 mr = *(const float4*)(&MR[j]);
        oo += wo.x * gf.x + wo.y * gf.y + wo.z * gf.z + wo.w * gf.w;
        rr += wq.x * mr.x + wq.y * mr.y + wq.z * mr.z + wq.w * mr.w;
    }
    out[(size_t)g * 256 + d] = oo + 0.2f * rr;
}

// ---------------- launch ----------------
extern "C" void kernel_launch(void* const* d_in, const int* in_sizes, int n_in,
                              void* d_out, int out_size, void* d_ws, size_t ws_size,
                              hipStream_t stream)
{
    const float* h        = (const float*)d_in[0];
    const int*   batch    = (const int*)d_in[1];
    const int*   cdr      = (const int*)d_in[2];   // bool mask arrives as int32
    const int*   ifm      = (const int*)d_in[3];   // bool mask arrives as int32
    const float* ln_kv_w  = (const float*)d_in[4];
    const float* ln_kv_b  = (const float*)d_in[5];
    const float* ln_q_w   = (const float*)d_in[6];
    const float* ln_q_b   = (const float*)d_in[7];
    const float* Wk       = (const float*)d_in[8];
    const float* Wv       = (const float*)d_in[9];
    const float* Wq       = (const float*)d_in[10];
    const float* Wres     = (const float*)d_in[11];
    const float* Wout     = (const float*)d_in[12];
    const float* cdr_b    = (const float*)d_in[13];
    const float* if_b     = (const float*)d_in[14];
    const float* lsc      = (const float*)d_in[15];

    const int N = in_sizes[0] / 256;   // 262144
    const int B = out_size / 256;      // 1024

    int*    start    = (int*)d_ws;                         // (B+1) ints (8 KB reserved)
    float*  mean_raw = (float*)((char*)d_ws + 8192);       // B*256 floats (1 MB)
    float*  w_eff    = mean_raw + (size_t)B * 256;         // B*8*256 floats (8 MB)
    float*  u_norm   = w_eff + (size_t)B * 2048;           // B*8*256 floats (8 MB)
    float*  psum     = u_norm + (size_t)B * 2048;          // 4B*256 floats (4 MB)
    float*  pmax     = psum + (size_t)B * 1024;            // 4B*256 floats (4 MB)
    float*  mbias    = pmax + (size_t)B * 1024;            // N floats (1 MB)
    float2* stat     = (float2*)(mbias + (size_t)N);       // N float2 (2 MB)

    k_offsets<<<(N + 255) / 256, 256, 0, stream>>>(batch, cdr, ifm, cdr_b, if_b,
                                                   start, mbias, N, B);
    k_pool<<<B * 4, 256, 0, stream>>>(h, start, psum, pmax, stat);
    k_q<<<B, 256, 0, stream>>>(psum, pmax, start, Wq, Wk, ln_q_w, ln_q_b, ln_kv_w,
                               lsc, mean_raw, w_eff);
    k_attn<<<B, 256, 0, stream>>>(h, start, mbias, stat, ln_kv_w, ln_kv_b, w_eff, u_norm);
    k_out<<<B, 256, 0, stream>>>(u_norm, mean_raw, Wv, Wout, Wres, (float*)d_out);
}

// Round 9
// 619.719 us; speedup vs baseline: 1.1477x; 1.0534x over previous
//
#include <hip/hip_runtime.h>

// ---------------- Kernel 0: segment offsets + fused mask bias ----------------
__global__ void k_offsets(const int* __restrict__ batch, const int* __restrict__ cdr,
                          const int* __restrict__ ifm, const float* __restrict__ cdr_bias,
                          const float* __restrict__ iface_bias,
                          int* __restrict__ start, float* __restrict__ mbias,
                          int N, int B) {
    int i = blockIdx.x * blockDim.x + threadIdx.x;
    if (i >= N) return;
    mbias[i] = cdr_bias[0] * (float)cdr[i] + iface_bias[0] * (float)ifm[i];
    int b = batch[i];
    if (i == 0) {
        for (int g = 0; g <= b; ++g) start[g] = 0;
    } else {
        int pb = batch[i - 1];
        for (int g = pb + 1; g <= b; ++g) start[g] = i;
    }
    if (i == N - 1) {
        for (int g = b + 1; g <= B; ++g) start[g] = N;
    }
}

// ---------------- Fused per-graph kernel: pool -> q -> w_eff -> attn -> out ----------------
// One block per graph (1024 blocks = 4/CU, LDS 40.0 KB). All phases communicate via LDS;
// no intermediate global buffers. The attn phase re-reads this block's h-slice right after
// the pool phase read it (L3-warm: all blocks co-resident, 268 MB vs 256 MB L3, and no
// poison-fill can intervene).
// SMEM float layout (8448 floats = 33.8 KB), lifetimes strictly ordered:
//   pool:  PS [0,1024)  PM [1024,2048)
//   q:     X  [0,512)   QL [512,768)
//   w_eff: WE [768,2880)   (8 heads x 264 padded)
//   stats: STT[2880,4416)  (768 rows x {mu,rstd}; uniform-branch inline fallback beyond)
//   attn epilogue: UF = SMEM[0,8448) as [4][8][264]   (STT/WE dead; pre-write barrier)
//   merge: UN [0,2048)  GF [2048,2304)
// R8 BUG (fixed): PM reads were double-offset (PM[1024+d] on a base that already included
// +1024) -> max-pool half of X was garbage. Reads are base-relative: PM[d], PM[256+d], ...
// NOTE: plain __launch_bounds__(256) — a (256,4) min-waves hint capped VGPR at 64 and
// spilled u[32]/hv[32] to scratch (418 MB WRITE_SIZE, 2.3x slower). Do not re-add.
#define STAT_CAP 768

__global__ __launch_bounds__(256) void k_fused(
    const float* __restrict__ h, const int* __restrict__ start,
    const float* __restrict__ mbias,
    const float* __restrict__ lnkw, const float* __restrict__ lnkb,
    const float* __restrict__ Wq, const float* __restrict__ Wk,
    const float* __restrict__ ln_q_w, const float* __restrict__ ln_q_b,
    const float* __restrict__ logit_scale,
    const float* __restrict__ Wv, const float* __restrict__ Wout,
    const float* __restrict__ Wres,
    float* __restrict__ out)
{
    const int g = blockIdx.x;
    const int tid = threadIdx.x;
    const int w = tid >> 6;
    const int l = tid & 63;
    const int hh = l >> 3;
    const int p = l & 7;
    const int s = start[g], e = start[g + 1];
    const int len = e - s;

    __shared__ __align__(16) float SMEM[8448];
    __shared__ __align__(16) float hbuf[4][288];
    __shared__ __align__(16) float MR[256];
    __shared__ float MW[4][8], ZW[4][8], SW[4][8], FG[4][8], IZ[8], SG[8];
    __shared__ float rs[4], rq[4];

    float* const PS  = SMEM;            // [4][256]
    float* const PM  = SMEM + 1024;     // [4][256]
    float* const X   = SMEM;            // [512]
    float* const QL  = SMEM + 512;      // [256]
    float* const WE  = SMEM + 768;      // [8][264]
    float* const STT = SMEM + 2880;     // [768][2]

    // ================= Phase P: pooling + per-row LN stats =================
    {
        float4 sm = make_float4(0.f, 0.f, 0.f, 0.f);
        float4 mx = make_float4(-INFINITY, -INFINITY, -INFINITY, -INFINITY);

        #define PROC(v, rowidx) do { \
            sm.x += (v).x; sm.y += (v).y; sm.z += (v).z; sm.w += (v).w; \
            mx.x = fmaxf(mx.x, (v).x); mx.y = fmaxf(mx.y, (v).y); \
            mx.z = fmaxf(mx.z, (v).z); mx.w = fmaxf(mx.w, (v).w); \
            float s1_ = ((v).x + (v).y) + ((v).z + (v).w); \
            float s2_ = fmaf((v).x, (v).x, fmaf((v).y, (v).y, fmaf((v).z, (v).z, (v).w * (v).w))); \
            s1_ += __shfl_xor(s1_, 1);  s2_ += __shfl_xor(s2_, 1); \
            s1_ += __shfl_xor(s1_, 2);  s2_ += __shfl_xor(s2_, 2); \
            s1_ += __shfl_xor(s1_, 4);  s2_ += __shfl_xor(s2_, 4); \
            s1_ += __shfl_xor(s1_, 8);  s2_ += __shfl_xor(s2_, 8); \
            s1_ += __shfl_xor(s1_, 16); s2_ += __shfl_xor(s2_, 16); \
            s1_ += __shfl_xor(s1_, 32); s2_ += __shfl_xor(s2_, 32); \
            const int ri_ = (rowidx) - s; \
            if (l == 0 && ri_ < STAT_CAP) { \
                const float mu_ = s1_ * (1.f / 256.f); \
                const float var_ = s2_ * (1.f / 256.f) - mu_ * mu_; \
                *(float2*)(&STT[2 * ri_]) = make_float2(mu_, rsqrtf(var_ + 1e-5f)); \
            } } while (0)

        int n = s + w;
        if (n + 12 < e) {
            float4 f0 = *(const float4*)(h + (size_t)(n)      * 256 + l * 4);
            float4 f1 = *(const float4*)(h + (size_t)(n + 4)  * 256 + l * 4);
            float4 f2 = *(const float4*)(h + (size_t)(n + 8)  * 256 + l * 4);
            float4 f3 = *(const float4*)(h + (size_t)(n + 12) * 256 + l * 4);
            for (; n + 28 < e; n += 16) {
                PROC(f0, n);      f0 = *(const float4*)(h + (size_t)(n + 16) * 256 + l * 4);
                PROC(f1, n + 4);  f1 = *(const float4*)(h + (size_t)(n + 20) * 256 + l * 4);
                PROC(f2, n + 8);  f2 = *(const float4*)(h + (size_t)(n + 24) * 256 + l * 4);
                PROC(f3, n + 12); f3 = *(const float4*)(h + (size_t)(n + 28) * 256 + l * 4);
            }
            PROC(f0, n); PROC(f1, n + 4); PROC(f2, n + 8); PROC(f3, n + 12);
            n += 16;
        }
        for (; n < e; n += 4) {
            const float4 a = *(const float4*)(h + (size_t)n * 256 + l * 4);
            PROC(a, n);
        }
        #undef PROC

        *(float4*)(&PS[w * 256 + l * 4]) = sm;
        *(float4*)(&PM[w * 256 + l * 4]) = mx;
    }
    __syncthreads();

    const int d = tid;
    {
        const float sum = (PS[d] + PS[256 + d]) + (PS[512 + d] + PS[768 + d]);
        const float mxv = fmaxf(fmaxf(PM[d], PM[256 + d]),
                                fmaxf(PM[512 + d], PM[768 + d]));   // base-relative (R8 fix)
        const float mean = sum / (float)len;
        MR[d] = mean;
        X[d] = mean;          // overwrites PS[0][d] — slot owned by this thread
        X[256 + d] = mxv;     // overwrites PS[1][d] — slot owned by this thread
    }
    __syncthreads();

    // ================= Phase Q: q GEMV -> LN -> folded w_eff (LDS) =================
    {
        float q = 0.f;
        const float* wqr = Wq + (size_t)d * 512;
        #pragma unroll 8
        for (int j = 0; j < 512; j += 4) {
            float4 w4 = *(const float4*)(wqr + j);
            q += w4.x * X[j] + w4.y * X[j + 1] + w4.z * X[j + 2] + w4.w * X[j + 3];
        }
        float s1 = q, s2 = q * q;
        #pragma unroll
        for (int off = 1; off < 64; off <<= 1) {
            s1 += __shfl_xor(s1, off);
            s2 += __shfl_xor(s2, off);
        }
        if ((d & 63) == 0) { rs[d >> 6] = s1; rq[d >> 6] = s2; }
        __syncthreads();
        const float t1 = rs[0] + rs[1] + rs[2] + rs[3];
        const float t2 = rq[0] + rq[1] + rq[2] + rq[3];
        const float mu = t1 * (1.f / 256.f);
        const float var = t2 * (1.f / 256.f) - mu * mu;
        const float rstd = rsqrtf(var + 1e-5f);
        QL[d] = (q - mu) * rstd * ln_q_w[d] + ln_q_b[d];
        __syncthreads();

        const float scale = logit_scale[0] * 0.17677669529663687f; // 1/sqrt(32)
        const float fold = scale * lnkw[d];
        #pragma unroll
        for (int h2 = 0; h2 < 8; ++h2) {
            float a = 0.f;
            #pragma unroll 8
            for (int r = 0; r < 32; ++r) {
                a += Wk[(size_t)(h2 * 32 + r) * 256 + d] * QL[h2 * 32 + r];
            }
            WE[h2 * 264 + d] = a * fold;
        }
    }
    __syncthreads();

    // ================= Phase A: logits on raw x + online segment softmax =================
    float we[32];
    #pragma unroll
    for (int r = 0; r < 8; ++r) {
        float4 t = *(const float4*)(&WE[hh * 264 + p * 32 + r * 4]);
        we[4 * r + 0] = t.x; we[4 * r + 1] = t.y; we[4 * r + 2] = t.z; we[4 * r + 3] = t.w;
    }
    float s1h = 0.f;
    #pragma unroll
    for (int r = 0; r < 32; ++r) s1h += we[r];
    s1h += __shfl_xor(s1h, 1);
    s1h += __shfl_xor(s1h, 2);
    s1h += __shfl_xor(s1h, 4);

    float m = -INFINITY, z = 0.f, sw = 0.f;
    float u[32];
    #pragma unroll
    for (int r = 0; r < 32; ++r) u[r] = 0.f;

    const int wofs = l * 4 + ((l >> 3) << 2); // padded offset of j = l*4
    const int rofs = p * 36;                  // padded base of chunk p

    {
        int n = s + w;
        float4 x0 = make_float4(0.f, 0.f, 0.f, 0.f);
        float4 x1 = x0;
        float b0 = 0.f, b1 = 0.f;
        if (n < e)     { x0 = *(const float4*)(h + (size_t)n * 256 + l * 4);       b0 = mbias[n]; }
        if (n + 4 < e) { x1 = *(const float4*)(h + (size_t)(n + 4) * 256 + l * 4); b1 = mbias[n + 4]; }

        while (n < e) {
            const float4 xc = x0;
            const float bc = b0;
            x0 = x1; b0 = b1;
            if (n + 8 < e) {                   // depth-2 rolling prefetch
                x1 = *(const float4*)(h + (size_t)(n + 8) * 256 + l * 4);
                b1 = mbias[n + 8];
            }

            float mu, rstd;
            const int ri = n - s;              // wave-uniform
            if (ri < STAT_CAP) {
                const float2 tc = *(const float2*)(&STT[2 * ri]);
                mu = tc.x; rstd = tc.y;
            } else {                            // inline fallback (never hit for this data)
                float s1 = (xc.x + xc.y) + (xc.z + xc.w);
                float s2 = fmaf(xc.x, xc.x, fmaf(xc.y, xc.y, fmaf(xc.z, xc.z, xc.w * xc.w)));
                #pragma unroll
                for (int off = 1; off < 64; off <<= 1) {
                    s1 += __shfl_xor(s1, off);
                    s2 += __shfl_xor(s2, off);
                }
                mu = s1 * (1.f / 256.f);
                rstd = rsqrtf(s2 * (1.f / 256.f) - mu * mu + 1e-5f);
            }

            *(float4*)(&hbuf[w][wofs]) = xc;   // RAW x
            asm volatile("s_waitcnt lgkmcnt(0)" ::: "memory");

            float hv[32];
            #pragma unroll
            for (int r = 0; r < 8; ++r) {
                float4 t = *(const float4*)(&hbuf[w][rofs + r * 4]);
                hv[4 * r + 0] = t.x; hv[4 * r + 1] = t.y; hv[4 * r + 2] = t.z; hv[4 * r + 3] = t.w;
            }
            float d0 = 0.f, d1 = 0.f, d2 = 0.f, d3 = 0.f;
            #pragma unroll
            for (int r = 0; r < 8; ++r) {
                d0 = fmaf(hv[4 * r + 0], we[4 * r + 0], d0);
                d1 = fmaf(hv[4 * r + 1], we[4 * r + 1], d1);
                d2 = fmaf(hv[4 * r + 2], we[4 * r + 2], d2);
                d3 = fmaf(hv[4 * r + 3], we[4 * r + 3], d3);
            }
            float dt = (d0 + d1) + (d2 + d3);
            dt += __shfl_xor(dt, 1);
            dt += __shfl_xor(dt, 2);
            dt += __shfl_xor(dt, 4);

            const float lv = fmaf(rstd, dt - mu * s1h, bc);
            const float nm = fmaxf(m, lv);
            const float ee = __expf(lv - nm);
            const float c = ee * rstd;
            if (__any(lv > m)) {               // max moved: rescale path
                const float a = __expf(m - nm);
                z = z * a + ee;
                sw = sw * a + c * mu;
                #pragma unroll
                for (int r = 0; r < 32; ++r) u[r] = u[r] * a + c * hv[r];
                m = nm;
            } else {
                z += ee;
                sw += c * mu;
                #pragma unroll
                for (int r = 0; r < 32; ++r) u[r] = fmaf(c, hv[r], u[r]);
            }
            n += 4;
        }
    }

    __syncthreads();   // all waves done with STT/WE before UF overwrites SMEM
    if (p == 0) { MW[w][hh] = m; ZW[w][hh] = z; SW[w][hh] = sw; }
    #pragma unroll
    for (int r = 0; r < 8; ++r) {
        float4 t = make_float4(u[4 * r], u[4 * r + 1], u[4 * r + 2], u[4 * r + 3]);
        *(float4*)(&SMEM[w * 2112 + hh * 264 + p * 32 + r * 4]) = t;   // UF[w][hh][..]
    }
    __syncthreads();

    if (tid < 8) {
        const float mg = fmaxf(fmaxf(MW[0][tid], MW[1][tid]),
                               fmaxf(MW[2][tid], MW[3][tid]));
        float zg = 0.f, sg = 0.f;
        #pragma unroll
        for (int ww = 0; ww < 4; ++ww) {
            const float f = __expf(MW[ww][tid] - mg);  // empty wave: exp(-inf)=0
            FG[ww][tid] = f;
            zg += ZW[ww][tid] * f;
            sg += SW[ww][tid] * f;
        }
        IZ[tid] = 1.f / zg;
        SG[tid] = sg;
    }
    __syncthreads();

    // merge 4 waves' partials -> u_norm (registers), then stage UN in LDS
    float un[8];
    {
        const float lwj = lnkw[tid], lbj = lnkb[tid];
        #pragma unroll
        for (int h2 = 0; h2 < 8; ++h2) {
            const float Uv = SMEM[0 * 2112 + h2 * 264 + tid] * FG[0][h2]
                           + SMEM[1 * 2112 + h2 * 264 + tid] * FG[1][h2]
                           + SMEM[2 * 2112 + h2 * 264 + tid] * FG[2][h2]
                           + SMEM[3 * 2112 + h2 * 264 + tid] * FG[3][h2];
            un[h2] = (Uv - SG[h2]) * IZ[h2] * lwj + lbj;
        }
    }
    __syncthreads();
    #pragma unroll
    for (int h2 = 0; h2 < 8; ++h2) SMEM[h2 * 256 + tid] = un[h2];   // UN [0,2048)
    __syncthreads();

    // ================= Phase O: g = Wv.UN(head), out = Wout.g + 0.2*Wres.mean =================
    {
        const int h5 = d >> 5;
        float acc = 0.f;
        const float* wvr = Wv + (size_t)d * 256;
        #pragma unroll 8
        for (int j = 0; j < 256; j += 4) {
            const float4 wv = *(const float4*)(wvr + j);
            const float4 uv = *(const float4*)(&SMEM[h5 * 256 + j]);
            acc += wv.x * uv.x + wv.y * uv.y + wv.z * uv.z + wv.w * uv.w;
        }
        SMEM[2048 + d] = acc;   // GF
    }
    __syncthreads();
    {
        float oo = 0.f, rr = 0.f;
        const float* wor = Wout + (size_t)d * 256;
        const float* wrr = Wres + (size_t)d * 256;
        #pragma unroll 8
        for (int j = 0; j < 256; j += 4) {
            const float4 wo = *(const float4*)(wor + j);
            const float4 wq = *(const float4*)(wrr + j);
            const float4 gf = *(const float4*)(&SMEM[2048 + j]);
            const float4 mr = *(const float4*)(&MR[j]);
            oo += wo.x * gf.x + wo.y * gf.y + wo.z * gf.z + wo.w * gf.w;
            rr += wq.x * mr.x + wq.y * mr.y + wq.z * mr.z + wq.w * mr.w;
        }
        out[(size_t)g * 256 + d] = oo + 0.2f * rr;
    }
}

// ---------------- launch ----------------
extern "C" void kernel_launch(void* const* d_in, const int* in_sizes, int n_in,
                              void* d_out, int out_size, void* d_ws, size_t ws_size,
                              hipStream_t stream)
{
    const float* h        = (const float*)d_in[0];
    const int*   batch    = (const int*)d_in[1];
    const int*   cdr      = (const int*)d_in[2];   // bool mask arrives as int32
    const int*   ifm      = (const int*)d_in[3];   // bool mask arrives as int32
    const float* ln_kv_w  = (const float*)d_in[4];
    const float* ln_kv_b  = (const float*)d_in[5];
    const float* ln_q_w   = (const float*)d_in[6];
    const float* ln_q_b   = (const float*)d_in[7];
    const float* Wk       = (const float*)d_in[8];
    const float* Wv       = (const float*)d_in[9];
    const float* Wq       = (const float*)d_in[10];
    const float* Wres     = (const float*)d_in[11];
    const float* Wout     = (const float*)d_in[12];
    const float* cdr_b    = (const float*)d_in[13];
    const float* if_b     = (const float*)d_in[14];
    const float* lsc      = (const float*)d_in[15];

    const int N = in_sizes[0] / 256;   // 262144
    const int B = out_size / 256;      // 1024

    int*   start = (int*)d_ws;                      // (B+1) ints (8 KB reserved)
    float* mbias = (float*)((char*)d_ws + 8192);    // N floats (1 MB)

    k_offsets<<<(N + 255) / 256, 256, 0, stream>>>(batch, cdr, ifm, cdr_b, if_b,
                                                   start, mbias, N, B);
    k_fused<<<B, 256, 0, stream>>>(h, start, mbias, ln_kv_w, ln_kv_b,
                                   Wq, Wk, ln_q_w, ln_q_b, lsc,
                                   Wv, Wout, Wres, (float*)d_out);
}

// Round 10
// 611.300 us; speedup vs baseline: 1.1635x; 1.0138x over previous
//
#include <hip/hip_runtime.h>

// ---------------- Kernel 0: segment offsets + fused mask bias ----------------
__global__ void k_offsets(const int* __restrict__ batch, const int* __restrict__ cdr,
                          const int* __restrict__ ifm, const float* __restrict__ cdr_bias,
                          const float* __restrict__ iface_bias,
                          int* __restrict__ start, float* __restrict__ mbias,
                          int N, int B) {
    int i = blockIdx.x * blockDim.x + threadIdx.x;
    if (i >= N) return;
    mbias[i] = cdr_bias[0] * (float)cdr[i] + iface_bias[0] * (float)ifm[i];
    int b = batch[i];
    if (i == 0) {
        for (int g = 0; g <= b; ++g) start[g] = 0;
    } else {
        int pb = batch[i - 1];
        for (int g = pb + 1; g <= b; ++g) start[g] = i;
    }
    if (i == N - 1) {
        for (int g = b + 1; g <= B; ++g) start[g] = N;
    }
}

// ---------------- Fused per-graph kernel: pool -> q -> w_eff -> attn -> out ----------------
// One block per graph (1024 blocks = 4/CU, LDS ~35.4 KB). All phases communicate via LDS.
// R10: attn loop processes a PAIR of consecutive nodes per iteration (stride 8 per wave):
// halves the number of serial {fence->reads->dot->shuffles->exp->update} chain traversals
// (the measured bottleneck: VALUBusy 29%, HBM 10% in R9). Both rows' dot/update read LDS
// transiently (no hv[32] arrays -> VGPR stays ~110 < 128, preserving 4 blocks/CU).
// Row buffer HB is ALIASED into SMEM[0,2304) (X/QL/PS/PM dead during the loop; WE is
// register-copied before it, protected by an extra barrier) -> LDS net DECREASES.
// SMEM float layout (8448 floats), lifetimes strictly ordered:
//   pool:  PS [0,1024)  PM [1024,2048)          (+ STT [2880,4416) written here)
//   q:     X  [0,512)   QL [512,768)   WE [768,2880)
//   attn:  HB [0,2304) (4 waves x 2 rows x 288)  STT [2880,4416)
//   attn epilogue: UF = SMEM[0,8448) as [4][8][264]
//   merge: UN [0,2048)  GF [2048,2304)
// NOTE: plain __launch_bounds__(256) — a (256,4) min-waves hint capped VGPR at 64 and
// spilled to scratch (418 MB WRITE_SIZE, 2.3x slower). Do not re-add.
#define STAT_CAP 768

__global__ __launch_bounds__(256) void k_fused(
    const float* __restrict__ h, const int* __restrict__ start,
    const float* __restrict__ mbias,
    const float* __restrict__ lnkw, const float* __restrict__ lnkb,
    const float* __restrict__ Wq, const float* __restrict__ Wk,
    const float* __restrict__ ln_q_w, const float* __restrict__ ln_q_b,
    const float* __restrict__ logit_scale,
    const float* __restrict__ Wv, const float* __restrict__ Wout,
    const float* __restrict__ Wres,
    float* __restrict__ out)
{
    const int g = blockIdx.x;
    const int tid = threadIdx.x;
    const int w = tid >> 6;
    const int l = tid & 63;
    const int hh = l >> 3;
    const int p = l & 7;
    const int s = start[g], e = start[g + 1];
    const int len = e - s;

    __shared__ __align__(16) float SMEM[8448];
    __shared__ __align__(16) float MR[256];
    __shared__ float MW[4][8], ZW[4][8], SW[4][8], FG[4][8], IZ[8], SG[8];
    __shared__ float rs[4], rq[4];

    float* const PS  = SMEM;            // [4][256]
    float* const PM  = SMEM + 1024;     // [4][256]
    float* const X   = SMEM;            // [512]
    float* const QL  = SMEM + 512;      // [256]
    float* const WE  = SMEM + 768;      // [8][264]
    float* const STT = SMEM + 2880;     // [768][2]
    float* const HB  = SMEM;            // attn row buffer alias [0,2304)

    // ================= Phase P: pooling + per-row LN stats =================
    {
        float4 sm = make_float4(0.f, 0.f, 0.f, 0.f);
        float4 mx = make_float4(-INFINITY, -INFINITY, -INFINITY, -INFINITY);

        #define PROC(v, rowidx) do { \
            sm.x += (v).x; sm.y += (v).y; sm.z += (v).z; sm.w += (v).w; \
            mx.x = fmaxf(mx.x, (v).x); mx.y = fmaxf(mx.y, (v).y); \
            mx.z = fmaxf(mx.z, (v).z); mx.w = fmaxf(mx.w, (v).w); \
            float s1_ = ((v).x + (v).y) + ((v).z + (v).w); \
            float s2_ = fmaf((v).x, (v).x, fmaf((v).y, (v).y, fmaf((v).z, (v).z, (v).w * (v).w))); \
            s1_ += __shfl_xor(s1_, 1);  s2_ += __shfl_xor(s2_, 1); \
            s1_ += __shfl_xor(s1_, 2);  s2_ += __shfl_xor(s2_, 2); \
            s1_ += __shfl_xor(s1_, 4);  s2_ += __shfl_xor(s2_, 4); \
            s1_ += __shfl_xor(s1_, 8);  s2_ += __shfl_xor(s2_, 8); \
            s1_ += __shfl_xor(s1_, 16); s2_ += __shfl_xor(s2_, 16); \
            s1_ += __shfl_xor(s1_, 32); s2_ += __shfl_xor(s2_, 32); \
            const int ri_ = (rowidx) - s; \
            if (l == 0 && ri_ < STAT_CAP) { \
                const float mu_ = s1_ * (1.f / 256.f); \
                const float var_ = s2_ * (1.f / 256.f) - mu_ * mu_; \
                *(float2*)(&STT[2 * ri_]) = make_float2(mu_, rsqrtf(var_ + 1e-5f)); \
            } } while (0)

        int n = s + w;
        if (n + 12 < e) {
            float4 f0 = *(const float4*)(h + (size_t)(n)      * 256 + l * 4);
            float4 f1 = *(const float4*)(h + (size_t)(n + 4)  * 256 + l * 4);
            float4 f2 = *(const float4*)(h + (size_t)(n + 8)  * 256 + l * 4);
            float4 f3 = *(const float4*)(h + (size_t)(n + 12) * 256 + l * 4);
            for (; n + 28 < e; n += 16) {
                PROC(f0, n);      f0 = *(const float4*)(h + (size_t)(n + 16) * 256 + l * 4);
                PROC(f1, n + 4);  f1 = *(const float4*)(h + (size_t)(n + 20) * 256 + l * 4);
                PROC(f2, n + 8);  f2 = *(const float4*)(h + (size_t)(n + 24) * 256 + l * 4);
                PROC(f3, n + 12); f3 = *(const float4*)(h + (size_t)(n + 28) * 256 + l * 4);
            }
            PROC(f0, n); PROC(f1, n + 4); PROC(f2, n + 8); PROC(f3, n + 12);
            n += 16;
        }
        for (; n < e; n += 4) {
            const float4 a = *(const float4*)(h + (size_t)n * 256 + l * 4);
            PROC(a, n);
        }
        #undef PROC

        *(float4*)(&PS[w * 256 + l * 4]) = sm;
        *(float4*)(&PM[w * 256 + l * 4]) = mx;
    }
    __syncthreads();

    const int d = tid;
    {
        const float sum = (PS[d] + PS[256 + d]) + (PS[512 + d] + PS[768 + d]);
        const float mxv = fmaxf(fmaxf(PM[d], PM[256 + d]),
                                fmaxf(PM[512 + d], PM[768 + d]));   // base-relative (R8 fix)
        const float mean = sum / (float)len;
        MR[d] = mean;
        X[d] = mean;
        X[256 + d] = mxv;
    }
    __syncthreads();

    // ================= Phase Q: q GEMV -> LN -> folded w_eff (LDS) =================
    {
        float q = 0.f;
        const float* wqr = Wq + (size_t)d * 512;
        #pragma unroll 8
        for (int j = 0; j < 512; j += 4) {
            float4 w4 = *(const float4*)(wqr + j);
            q += w4.x * X[j] + w4.y * X[j + 1] + w4.z * X[j + 2] + w4.w * X[j + 3];
        }
        float s1 = q, s2 = q * q;
        #pragma unroll
        for (int off = 1; off < 64; off <<= 1) {
            s1 += __shfl_xor(s1, off);
            s2 += __shfl_xor(s2, off);
        }
        if ((d & 63) == 0) { rs[d >> 6] = s1; rq[d >> 6] = s2; }
        __syncthreads();
        const float t1 = rs[0] + rs[1] + rs[2] + rs[3];
        const float t2 = rq[0] + rq[1] + rq[2] + rq[3];
        const float mu = t1 * (1.f / 256.f);
        const float var = t2 * (1.f / 256.f) - mu * mu;
        const float rstd = rsqrtf(var + 1e-5f);
        QL[d] = (q - mu) * rstd * ln_q_w[d] + ln_q_b[d];
        __syncthreads();

        const float scale = logit_scale[0] * 0.17677669529663687f; // 1/sqrt(32)
        const float fold = scale * lnkw[d];
        #pragma unroll
        for (int h2 = 0; h2 < 8; ++h2) {
            float a = 0.f;
            #pragma unroll 8
            for (int r = 0; r < 32; ++r) {
                a += Wk[(size_t)(h2 * 32 + r) * 256 + d] * QL[h2 * 32 + r];
            }
            WE[h2 * 264 + d] = a * fold;
        }
    }
    __syncthreads();

    // ================= Phase A: pair-ILP logits + online segment softmax =================
    float we[32];
    #pragma unroll
    for (int r = 0; r < 8; ++r) {
        float4 t = *(const float4*)(&WE[hh * 264 + p * 32 + r * 4]);
        we[4 * r + 0] = t.x; we[4 * r + 1] = t.y; we[4 * r + 2] = t.z; we[4 * r + 3] = t.w;
    }
    float s1h = 0.f;
    #pragma unroll
    for (int r = 0; r < 32; ++r) s1h += we[r];
    s1h += __shfl_xor(s1h, 1);
    s1h += __shfl_xor(s1h, 2);
    s1h += __shfl_xor(s1h, 4);
    __syncthreads();   // WE fully consumed -> HB may overwrite [768,2304)

    float m = -INFINITY, z = 0.f, sw = 0.f;
    float u[32];
    #pragma unroll
    for (int r = 0; r < 32; ++r) u[r] = 0.f;

    const int wofs = l * 4 + ((l >> 3) << 2); // padded offset of j = l*4 (288-stride rows)
    const int rofs = p * 36;                  // padded base of chunk p
    float* const rowA = HB + w * 576;
    float* const rowB = HB + w * 576 + 288;

    {
        int n = s + 2 * w;
        float4 xa0 = make_float4(0.f, 0.f, 0.f, 0.f), xb0 = xa0, xa1 = xa0, xb1 = xa0;
        float ba0 = 0.f, bb0 = 0.f, ba1 = 0.f, bb1 = 0.f;
        if (n < e)     { xa0 = *(const float4*)(h + (size_t)n * 256 + l * 4);       ba0 = mbias[n]; }
        if (n + 1 < e) { xb0 = *(const float4*)(h + (size_t)(n + 1) * 256 + l * 4); bb0 = mbias[n + 1]; }
        if (n + 8 < e) { xa1 = *(const float4*)(h + (size_t)(n + 8) * 256 + l * 4); ba1 = mbias[n + 8]; }
        if (n + 9 < e) { xb1 = *(const float4*)(h + (size_t)(n + 9) * 256 + l * 4); bb1 = mbias[n + 9]; }

        while (n < e) {
            const float4 xA = xa0, xB = xb0;
            const float bA = ba0, bB = bb0;
            xa0 = xa1; xb0 = xb1; ba0 = ba1; bb0 = bb1;
            if (n + 16 < e) { xa1 = *(const float4*)(h + (size_t)(n + 16) * 256 + l * 4); ba1 = mbias[n + 16]; }
            if (n + 17 < e) { xb1 = *(const float4*)(h + (size_t)(n + 17) * 256 + l * 4); bb1 = mbias[n + 17]; }

            // per-row LN stats (wave-uniform branches)
            const int ri0 = n - s;
            const bool hasB = (n + 1 < e);
            float muA, rsA, muB, rsB;
            if (ri0 < STAT_CAP) {
                const float2 t = *(const float2*)(&STT[2 * ri0]);
                muA = t.x; rsA = t.y;
            } else {
                float s1 = (xA.x + xA.y) + (xA.z + xA.w);
                float s2 = fmaf(xA.x, xA.x, fmaf(xA.y, xA.y, fmaf(xA.z, xA.z, xA.w * xA.w)));
                #pragma unroll
                for (int off = 1; off < 64; off <<= 1) { s1 += __shfl_xor(s1, off); s2 += __shfl_xor(s2, off); }
                muA = s1 * (1.f / 256.f);
                rsA = rsqrtf(s2 * (1.f / 256.f) - muA * muA + 1e-5f);
            }
            if (hasB) {
                if (ri0 + 1 < STAT_CAP) {
                    const float2 t = *(const float2*)(&STT[2 * ri0 + 2]);
                    muB = t.x; rsB = t.y;
                } else {
                    float s1 = (xB.x + xB.y) + (xB.z + xB.w);
                    float s2 = fmaf(xB.x, xB.x, fmaf(xB.y, xB.y, fmaf(xB.z, xB.z, xB.w * xB.w)));
                    #pragma unroll
                    for (int off = 1; off < 64; off <<= 1) { s1 += __shfl_xor(s1, off); s2 += __shfl_xor(s2, off); }
                    muB = s1 * (1.f / 256.f);
                    rsB = rsqrtf(s2 * (1.f / 256.f) - muB * muB + 1e-5f);
                }
            } else { muB = 0.f; rsB = 0.f; }

            *(float4*)(rowA + wofs) = xA;      // RAW x, both rows, one fence
            *(float4*)(rowB + wofs) = xB;
            asm volatile("s_waitcnt lgkmcnt(0)" ::: "memory");

            // two interleaved dots (transient LDS reads; rofs pattern is conflict-free)
            float dA0 = 0.f, dA1 = 0.f, dA2 = 0.f, dA3 = 0.f;
            float dB0 = 0.f, dB1 = 0.f, dB2 = 0.f, dB3 = 0.f;
            #pragma unroll
            for (int r = 0; r < 8; ++r) {
                const float4 ta = *(const float4*)(rowA + rofs + r * 4);
                const float4 tb = *(const float4*)(rowB + rofs + r * 4);
                dA0 = fmaf(ta.x, we[4 * r + 0], dA0); dA1 = fmaf(ta.y, we[4 * r + 1], dA1);
                dA2 = fmaf(ta.z, we[4 * r + 2], dA2); dA3 = fmaf(ta.w, we[4 * r + 3], dA3);
                dB0 = fmaf(tb.x, we[4 * r + 0], dB0); dB1 = fmaf(tb.y, we[4 * r + 1], dB1);
                dB2 = fmaf(tb.z, we[4 * r + 2], dB2); dB3 = fmaf(tb.w, we[4 * r + 3], dB3);
            }
            float dtA = (dA0 + dA1) + (dA2 + dA3);
            float dtB = (dB0 + dB1) + (dB2 + dB3);
            dtA += __shfl_xor(dtA, 1); dtB += __shfl_xor(dtB, 1);
            dtA += __shfl_xor(dtA, 2); dtB += __shfl_xor(dtB, 2);
            dtA += __shfl_xor(dtA, 4); dtB += __shfl_xor(dtB, 4);

            const float lvA = fmaf(rsA, dtA - muA * s1h, bA);
            const float lvB = hasB ? fmaf(rsB, dtB - muB * s1h, bB) : -INFINITY;

            const float nm = fmaxf(m, fmaxf(lvA, lvB));
            const float eA = __expf(lvA - nm);
            const float eB = __expf(lvB - nm);       // exp(-inf)=0 when !hasB
            const float cA = eA * rsA;
            const float cB = eB * rsB;               // 0*0=0 when !hasB
            if (__any(nm > m)) {                     // max moved: rescale path
                const float a = __expf(m - nm);      // exp(-inf)=0 on first pair
                z = z * a + (eA + eB);
                sw = sw * a + (cA * muA + cB * muB);
                #pragma unroll
                for (int r = 0; r < 8; ++r) {
                    const float4 ta = *(const float4*)(rowA + rofs + r * 4);
                    const float4 tb = *(const float4*)(rowB + rofs + r * 4);
                    u[4 * r + 0] = fmaf(u[4 * r + 0], a, fmaf(cA, ta.x, cB * tb.x));
                    u[4 * r + 1] = fmaf(u[4 * r + 1], a, fmaf(cA, ta.y, cB * tb.y));
                    u[4 * r + 2] = fmaf(u[4 * r + 2], a, fmaf(cA, ta.z, cB * tb.z));
                    u[4 * r + 3] = fmaf(u[4 * r + 3], a, fmaf(cA, ta.w, cB * tb.w));
                }
                m = nm;
            } else {                                 // common path: 2 FMA per element per pair
                z += eA + eB;
                sw += cA * muA + cB * muB;
                #pragma unroll
                for (int r = 0; r < 8; ++r) {
                    const float4 ta = *(const float4*)(rowA + rofs + r * 4);
                    const float4 tb = *(const float4*)(rowB + rofs + r * 4);
                    u[4 * r + 0] = fmaf(cA, ta.x, fmaf(cB, tb.x, u[4 * r + 0]));
                    u[4 * r + 1] = fmaf(cA, ta.y, fmaf(cB, tb.y, u[4 * r + 1]));
                    u[4 * r + 2] = fmaf(cA, ta.z, fmaf(cB, tb.z, u[4 * r + 2]));
                    u[4 * r + 3] = fmaf(cA, ta.w, fmaf(cB, tb.w, u[4 * r + 3]));
                }
            }
            n += 8;
        }
    }

    __syncthreads();   // all waves done with STT/HB before UF overwrites SMEM
    if (p == 0) { MW[w][hh] = m; ZW[w][hh] = z; SW[w][hh] = sw; }
    #pragma unroll
    for (int r = 0; r < 8; ++r) {
        float4 t = make_float4(u[4 * r], u[4 * r + 1], u[4 * r + 2], u[4 * r + 3]);
        *(float4*)(&SMEM[w * 2112 + hh * 264 + p * 32 + r * 4]) = t;   // UF[w][hh][..]
    }
    __syncthreads();

    if (tid < 8) {
        const float mg = fmaxf(fmaxf(MW[0][tid], MW[1][tid]),
                               fmaxf(MW[2][tid], MW[3][tid]));
        float zg = 0.f, sg = 0.f;
        #pragma unroll
        for (int ww = 0; ww < 4; ++ww) {
            const float f = __expf(MW[ww][tid] - mg);  // empty wave: exp(-inf)=0
            FG[ww][tid] = f;
            zg += ZW[ww][tid] * f;
            sg += SW[ww][tid] * f;
        }
        IZ[tid] = 1.f / zg;
        SG[tid] = sg;
    }
    __syncthreads();

    // merge 4 waves' partials -> u_norm (registers), then stage UN in LDS
    float un[8];
    {
        const float lwj = lnkw[tid], lbj = lnkb[tid];
        #pragma unroll
        for (int h2 = 0; h2 < 8; ++h2) {
            const float Uv = SMEM[0 * 2112 + h2 * 264 + tid] * FG[0][h2]
                           + SMEM[1 * 2112 + h2 * 264 + tid] * FG[1][h2]
                           + SMEM[2 * 2112 + h2 * 264 + tid] * FG[2][h2]
                           + SMEM[3 * 2112 + h2 * 264 + tid] * FG[3][h2];
            un[h2] = (Uv - SG[h2]) * IZ[h2] * lwj + lbj;
        }
    }
    __syncthreads();
    #pragma unroll
    for (int h2 = 0; h2 < 8; ++h2) SMEM[h2 * 256 + tid] = un[h2];   // UN [0,2048)
    __syncthreads();

    // ================= Phase O: g = Wv.UN(head), out = Wout.g + 0.2*Wres.mean =================
    {
        const int h5 = d >> 5;
        float acc = 0.f;
        const float* wvr = Wv + (size_t)d * 256;
        #pragma unroll 8
        for (int j = 0; j < 256; j += 4) {
            const float4 wv = *(const float4*)(wvr + j);
            const float4 uv = *(const float4*)(&SMEM[h5 * 256 + j]);
            acc += wv.x * uv.x + wv.y * uv.y + wv.z * uv.z + wv.w * uv.w;
        }
        SMEM[2048 + d] = acc;   // GF
    }
    __syncthreads();
    {
        float oo = 0.f, rr = 0.f;
        const float* wor = Wout + (size_t)d * 256;
        const float* wrr = Wres + (size_t)d * 256;
        #pragma unroll 8
        for (int j = 0; j < 256; j += 4) {
            const float4 wo = *(const float4*)(wor + j);
            const float4 wq = *(const float4*)(wrr + j);
            const float4 gf = *(const float4*)(&SMEM[2048 + j]);
            const float4 mr = *(const float4*)(&MR[j]);
            oo += wo.x * gf.x + wo.y * gf.y + wo.z * gf.z + wo.w * gf.w;
            rr += wq.x * mr.x + wq.y * mr.y + wq.z * mr.z + wq.w * mr.w;
        }
        out[(size_t)g * 256 + d] = oo + 0.2f * rr;
    }
}

// ---------------- launch ----------------
extern "C" void kernel_launch(void* const* d_in, const int* in_sizes, int n_in,
                              void* d_out, int out_size, void* d_ws, size_t ws_size,
                              hipStream_t stream)
{
    const float* h        = (const float*)d_in[0];
    const int*   batch    = (const int*)d_in[1];
    const int*   cdr      = (const int*)d_in[2];   // bool mask arrives as int32
    const int*   ifm      = (const int*)d_in[3];   // bool mask arrives as int32
    const float* ln_kv_w  = (const float*)d_in[4];
    const float* ln_kv_b  = (const float*)d_in[5];
    const float* ln_q_w   = (const float*)d_in[6];
    const float* ln_q_b   = (const float*)d_in[7];
    const float* Wk       = (const float*)d_in[8];
    const float* Wv       = (const float*)d_in[9];
    const float* Wq       = (const float*)d_in[10];
    const float* Wres     = (const float*)d_in[11];
    const float* Wout     = (const float*)d_in[12];
    const float* cdr_b    = (const float*)d_in[13];
    const float* if_b     = (const float*)d_in[14];
    const float* lsc      = (const float*)d_in[15];

    const int N = in_sizes[0] / 256;   // 262144
    const int B = out_size / 256;      // 1024

    int*   start = (int*)d_ws;                      // (B+1) ints (8 KB reserved)
    float* mbias = (float*)((char*)d_ws + 8192);    // N floats (1 MB)

    k_offsets<<<(N + 255) / 256, 256, 0, stream>>>(batch, cdr, ifm, cdr_b, if_b,
                                                   start, mbias, N, B);
    k_fused<<<B, 256, 0, stream>>>(h, start, mbias, ln_kv_w, ln_kv_b,
                                   Wq, Wk, ln_q_w, ln_q_b, lsc,
                                   Wv, Wout, Wres, (float*)d_out);
}